// Round 1
// baseline (801.859 us; speedup 1.0000x reference)
//
#include <hip/hip_runtime.h>

#define N_NODES 50000
#define N_EDGES 800000

__device__ __forceinline__ float lrelu(float x){ return x > 0.f ? x : 0.2f*x; }
__device__ __forceinline__ float eluf (float x){ return x > 0.f ? x : __expf(x)-1.f; }

// ---------------- CSR build ----------------
__global__ void k_hist(const int* __restrict__ dst, int* __restrict__ cnt){
  int e = blockIdx.x*256 + threadIdx.x;
  if (e < N_EDGES) atomicAdd(&cnt[dst[e]], 1);
}

__global__ void k_scan1(const int* __restrict__ cnt, int* __restrict__ offs, int* __restrict__ bsum){
  __shared__ int tmp[256];
  int tid = threadIdx.x; int i = blockIdx.x*256 + tid;
  int v = (i < N_NODES) ? cnt[i] : 0;
  tmp[tid] = v; __syncthreads();
  for (int d = 1; d < 256; d <<= 1){
    int t = (tid >= d) ? tmp[tid-d] : 0;
    __syncthreads();
    tmp[tid] += t;
    __syncthreads();
  }
  if (i < N_NODES) offs[i] = tmp[tid] - v;          // exclusive within chunk
  if (tid == 255) bsum[blockIdx.x] = tmp[tid];       // chunk total
}

__global__ void k_scan2(int* __restrict__ bsum, int nb){
  __shared__ int tmp[256];
  int tid = threadIdx.x;
  int v = (tid < nb) ? bsum[tid] : 0;
  tmp[tid] = v; __syncthreads();
  for (int d = 1; d < 256; d <<= 1){
    int t = (tid >= d) ? tmp[tid-d] : 0;
    __syncthreads();
    tmp[tid] += t;
    __syncthreads();
  }
  if (tid < nb) bsum[tid] = tmp[tid] - v;            // exclusive chunk offsets
}

__global__ void k_scan3(int* __restrict__ offs, const int* __restrict__ bsum, int* __restrict__ cur){
  int i = blockIdx.x*256 + threadIdx.x;
  if (i < N_NODES){
    int o = offs[i] + bsum[blockIdx.x];
    offs[i] = o; cur[i] = o;
  }
  if (i == 0) offs[N_NODES] = N_EDGES;
}

__global__ void k_scatter(const int* __restrict__ src, const int* __restrict__ dst,
                          int* __restrict__ cur, int* __restrict__ csr_src){
  int e = blockIdx.x*256 + threadIdx.x;
  if (e < N_EDGES){
    int pos = atomicAdd(&cur[dst[e]], 1);
    csr_src[pos] = src[e];
  }
}

// ---------------- GEMM: feat[N,HF] = h[N,128] @ W[128,HF] ----------------
// block: 256 thr = 16x16, tile 64 rows x 64 cols, 4x4 per thread, 2 K-chunks of 64
template<int HF>
__global__ __launch_bounds__(256) void k_gemm(const float* __restrict__ h,
                                              const float* __restrict__ W,
                                              float* __restrict__ feat){
  __shared__ float Wl[64*64];    // [k][j]
  __shared__ float hTl[64*68];   // [k][r], pad 68 breaks transpose-store conflicts
  int tid = threadIdx.x;
  int tx = tid & 15, ty = tid >> 4;
  int row0 = blockIdx.x * 64;
  int col0 = blockIdx.y * 64;
  float acc[4][4] = {};
  for (int kc = 0; kc < 2; ++kc){
    #pragma unroll
    for (int p = 0; p < 4; ++p){              // stage W chunk [64k x 64j]
      int k = p*16 + ty;
      float4 wv = *(const float4*)&W[(size_t)(kc*64 + k)*HF + col0 + tx*4];
      *(float4*)&Wl[k*64 + tx*4] = wv;
    }
    #pragma unroll
    for (int p = 0; p < 4; ++p){              // stage h chunk transposed
      int idx = (p*256 + tid)*4;              // 0..4095
      int r = idx >> 6, c = idx & 63;
      float4 hv = make_float4(0.f,0.f,0.f,0.f);
      int row = row0 + r;
      if (row < N_NODES) hv = *(const float4*)&h[(size_t)row*128 + kc*64 + c];
      hTl[(c+0)*68 + r] = hv.x;
      hTl[(c+1)*68 + r] = hv.y;
      hTl[(c+2)*68 + r] = hv.z;
      hTl[(c+3)*68 + r] = hv.w;
    }
    __syncthreads();
    #pragma unroll 8
    for (int k = 0; k < 64; ++k){
      float4 hv = *(const float4*)&hTl[k*68 + ty*4];
      float4 wv = *(const float4*)&Wl [k*64 + tx*4];
      acc[0][0] += hv.x*wv.x; acc[0][1] += hv.x*wv.y; acc[0][2] += hv.x*wv.z; acc[0][3] += hv.x*wv.w;
      acc[1][0] += hv.y*wv.x; acc[1][1] += hv.y*wv.y; acc[1][2] += hv.y*wv.z; acc[1][3] += hv.y*wv.w;
      acc[2][0] += hv.z*wv.x; acc[2][1] += hv.z*wv.y; acc[2][2] += hv.z*wv.z; acc[2][3] += hv.z*wv.w;
      acc[3][0] += hv.w*wv.x; acc[3][1] += hv.w*wv.y; acc[3][2] += hv.w*wv.z; acc[3][3] += hv.w*wv.w;
    }
    __syncthreads();
  }
  #pragma unroll
  for (int i = 0; i < 4; ++i){
    int row = row0 + ty*4 + i;
    if (row < N_NODES)
      *(float4*)&feat[(size_t)row*HF + col0 + tx*4] =
        make_float4(acc[i][0], acc[i][1], acc[i][2], acc[i][3]);
  }
}

// ---------------- attention logits el/er per (node, head) ----------------
template<int F>
__global__ void k_el(const float* __restrict__ feat, const float* __restrict__ al,
                     const float* __restrict__ ar, float* __restrict__ el,
                     float* __restrict__ er){
  int t = blockIdx.x*256 + threadIdx.x;
  if (t >= N_NODES*4) return;
  int n = t >> 2, h = t & 3;
  const float* fp  = feat + (size_t)n*(4*F) + h*F;
  const float* alp = al + h*F;
  const float* arp = ar + h*F;
  float sl = 0.f, sr = 0.f;
  #pragma unroll
  for (int i = 0; i < F; i += 4){
    float4 f = *(const float4*)&fp[i];
    float4 a = *(const float4*)&alp[i];
    float4 b = *(const float4*)&arp[i];
    sl += f.x*a.x + f.y*a.y + f.z*a.z + f.w*a.w;
    sr += f.x*b.x + f.y*b.y + f.z*b.z + f.w*b.w;
  }
  el[t] = sl; er[t] = sr;
}

// ---------------- per-dst-node softmax + aggregation (1 wave / node) ----------------
// F = head dim (32 or 64); HF = 4F. FINAL: mean over heads -> d_out[N,64]
template<int F, bool FINAL>
__global__ __launch_bounds__(256) void k_agg(const int* __restrict__ offs,
        const int* __restrict__ csr_src, const float* __restrict__ el,
        const float* __restrict__ er, const float* __restrict__ feat,
        const float* __restrict__ bias, float* __restrict__ out){
  int lane = threadIdx.x & 63;
  int n = (blockIdx.x*256 + threadIdx.x) >> 6;   // 12500 blocks * 4 waves = 50000 exactly
  if (n >= N_NODES) return;
  int beg = offs[n], end = offs[n+1];
  float4 er4 = ((const float4*)er)[n];

  // pass A: softmax denominator per head (max-subtraction skipped; logits O(1))
  float4 dsum = make_float4(0.f,0.f,0.f,0.f);
  for (int base = beg; base < end; base += 64){
    int e = base + lane;
    if (e < end){
      int s = csr_src[e];
      float4 l4 = ((const float4*)el)[s];
      dsum.x += __expf(lrelu(l4.x + er4.x));
      dsum.y += __expf(lrelu(l4.y + er4.y));
      dsum.z += __expf(lrelu(l4.z + er4.z));
      dsum.w += __expf(lrelu(l4.w + er4.w));
    }
  }
  #pragma unroll
  for (int m = 32; m >= 1; m >>= 1){
    dsum.x += __shfl_xor(dsum.x, m);
    dsum.y += __shfl_xor(dsum.y, m);
    dsum.z += __shfl_xor(dsum.z, m);
    dsum.w += __shfl_xor(dsum.w, m);
  }
  int h = lane >> 4;
  float er_h = (h==0) ? er4.x  : (h==1) ? er4.y  : (h==2) ? er4.z  : er4.w;
  float den  = (h==0) ? dsum.x : (h==1) ? dsum.y : (h==2) ? dsum.z : dsum.w;
  float rden = 1.f / fmaxf(den, 1e-9f);

  // pass B: weighted feature aggregation; lane owns PF consecutive features
  constexpr int PF = (F == 32) ? 2 : 4;
  float acc[PF] = {};
  for (int e = beg; e < end; ++e){
    int s = csr_src[e];
    float alpha = __expf(lrelu(el[s*4 + h] + er_h)) * rden;
    const float* fp = feat + (size_t)s*(4*F) + lane*PF;
    if (PF == 2){
      float2 v = *(const float2*)fp;
      acc[0] += alpha*v.x; acc[1] += alpha*v.y;
    } else {
      float4 v = *(const float4*)fp;
      acc[0] += alpha*v.x; acc[1] += alpha*v.y; acc[2] += alpha*v.z; acc[3] += alpha*v.w;
    }
  }

  if (!FINAL){
    float* op = out + (size_t)n*(4*F) + lane*PF;
    #pragma unroll
    for (int k = 0; k < PF; ++k)
      op[k] = eluf(acc[k] + bias[lane*PF + k]);
  } else {
    #pragma unroll
    for (int k = 0; k < PF; ++k){
      float v = acc[k] + bias[lane*PF + k];
      v += __shfl_xor(v, 16);
      v += __shfl_xor(v, 32);
      acc[k] = v * 0.25f;
    }
    if (lane < 16)
      *(float4*)&out[(size_t)n*64 + lane*4] = make_float4(acc[0],acc[1],acc[2],acc[3]);
  }
}

extern "C" void kernel_launch(void* const* d_in, const int* in_sizes, int n_in,
                              void* d_out, int out_size, void* d_ws, size_t ws_size,
                              hipStream_t stream){
  const float* x   = (const float*)d_in[0];
  const int*   src = (const int*)  d_in[1];
  const int*   dst = (const int*)  d_in[2];
  const float* W[4]  = {(const float*)d_in[3],  (const float*)d_in[7],
                        (const float*)d_in[11], (const float*)d_in[15]};
  const float* al[4] = {(const float*)d_in[4],  (const float*)d_in[8],
                        (const float*)d_in[12], (const float*)d_in[16]};
  const float* ar[4] = {(const float*)d_in[5],  (const float*)d_in[9],
                        (const float*)d_in[13], (const float*)d_in[17]};
  const float* b[4]  = {(const float*)d_in[6],  (const float*)d_in[10],
                        (const float*)d_in[14], (const float*)d_in[18]};

  char* ws = (char*)d_ws;
  float* bufH = (float*)(ws);                  // 50000*128*4 = 25,600,000
  float* feat = (float*)(ws + 25600000);       // 50000*256*4 = 51,200,000
  float* el   = (float*)(ws + 76800000);       // 800,000
  float* er   = (float*)(ws + 77600000);       // 800,000
  int*   offs = (int*)  (ws + 78400000);       // 200,004 (padded)
  int*   cur  = (int*)  (ws + 78600032);       // 200,000
  int*   bsum = (int*)  (ws + 78800032);       // 1,024
  int*   csr  = (int*)  (ws + 78801056);       // 3,200,000  (end ~82 MB)

  // ---- CSR build (per call; ws is re-poisoned) ----
  hipMemsetAsync(cur, 0, N_NODES*sizeof(int), stream);
  k_hist   <<<3125, 256, 0, stream>>>(dst, cur);
  k_scan1  <<<196,  256, 0, stream>>>(cur, offs, bsum);
  k_scan2  <<<1,    256, 0, stream>>>(bsum, 196);
  k_scan3  <<<196,  256, 0, stream>>>(offs, bsum, cur);
  k_scatter<<<3125, 256, 0, stream>>>(src, dst, cur, csr);

  // ---- layers 1..3 (HF=128, F=32) ----
  const float* hin = x;
  for (int l = 0; l < 3; ++l){
    k_gemm<128><<<dim3(782,2), 256, 0, stream>>>(hin, W[l], feat);
    k_el<32>   <<<782, 256, 0, stream>>>(feat, al[l], ar[l], el, er);
    k_agg<32,false><<<12500, 256, 0, stream>>>(offs, csr, el, er, feat, b[l], bufH);
    hin = bufH;
  }
  // ---- layer 4 (HF=256, F=64) + head-mean ----
  k_gemm<256><<<dim3(782,4), 256, 0, stream>>>(bufH, W[3], feat);
  k_el<64>   <<<782, 256, 0, stream>>>(feat, al[3], ar[3], el, er);
  k_agg<64,true><<<12500, 256, 0, stream>>>(offs, csr, el, er, feat, b[3], (float*)d_out);
}

// Round 2
// 728.529 us; speedup vs baseline: 1.1007x; 1.1007x over previous
//
#include <hip/hip_runtime.h>

#define N_NODES 50000
#define N_EDGES 800000

__device__ __forceinline__ float lrelu(float x){ return x > 0.f ? x : 0.2f*x; }
__device__ __forceinline__ float eluf (float x){ return x > 0.f ? x : __expf(x)-1.f; }

// ---------------- CSR build ----------------
__global__ void k_hist(const int* __restrict__ dst, int* __restrict__ cnt){
  int e = blockIdx.x*256 + threadIdx.x;
  if (e < N_EDGES) atomicAdd(&cnt[dst[e]], 1);
}

__global__ void k_scan1(const int* __restrict__ cnt, int* __restrict__ offs, int* __restrict__ bsum){
  __shared__ int tmp[256];
  int tid = threadIdx.x; int i = blockIdx.x*256 + tid;
  int v = (i < N_NODES) ? cnt[i] : 0;
  tmp[tid] = v; __syncthreads();
  for (int d = 1; d < 256; d <<= 1){
    int t = (tid >= d) ? tmp[tid-d] : 0;
    __syncthreads();
    tmp[tid] += t;
    __syncthreads();
  }
  if (i < N_NODES) offs[i] = tmp[tid] - v;          // exclusive within chunk
  if (tid == 255) bsum[blockIdx.x] = tmp[tid];       // chunk total
}

__global__ void k_scan2(int* __restrict__ bsum, int nb){
  __shared__ int tmp[256];
  int tid = threadIdx.x;
  int v = (tid < nb) ? bsum[tid] : 0;
  tmp[tid] = v; __syncthreads();
  for (int d = 1; d < 256; d <<= 1){
    int t = (tid >= d) ? tmp[tid-d] : 0;
    __syncthreads();
    tmp[tid] += t;
    __syncthreads();
  }
  if (tid < nb) bsum[tid] = tmp[tid] - v;            // exclusive chunk offsets
}

__global__ void k_scan3(int* __restrict__ offs, const int* __restrict__ bsum, int* __restrict__ cur){
  int i = blockIdx.x*256 + threadIdx.x;
  if (i < N_NODES){
    int o = offs[i] + bsum[blockIdx.x];
    offs[i] = o; cur[i] = o;
  }
  if (i == 0) offs[N_NODES] = N_EDGES;
}

__global__ void k_scatter(const int* __restrict__ src, const int* __restrict__ dst,
                          int* __restrict__ cur, int* __restrict__ csr_src,
                          int* __restrict__ csr_dst){
  int e = blockIdx.x*256 + threadIdx.x;
  if (e < N_EDGES){
    int d = dst[e];
    int pos = atomicAdd(&cur[d], 1);
    csr_src[pos] = src[e];
    csr_dst[pos] = d;
  }
}

// ---------------- GEMM: feat[N,HF] = h[N,128] @ W[128,HF] ----------------
template<int HF>
__global__ __launch_bounds__(256) void k_gemm(const float* __restrict__ h,
                                              const float* __restrict__ W,
                                              float* __restrict__ feat){
  __shared__ float Wl[64*64];    // [k][j]
  __shared__ float hTl[64*68];   // [k][r], pad 68 breaks transpose-store conflicts
  int tid = threadIdx.x;
  int tx = tid & 15, ty = tid >> 4;
  int row0 = blockIdx.x * 64;
  int col0 = blockIdx.y * 64;
  float acc[4][4] = {};
  for (int kc = 0; kc < 2; ++kc){
    #pragma unroll
    for (int p = 0; p < 4; ++p){              // stage W chunk [64k x 64j]
      int k = p*16 + ty;
      float4 wv = *(const float4*)&W[(size_t)(kc*64 + k)*HF + col0 + tx*4];
      *(float4*)&Wl[k*64 + tx*4] = wv;
    }
    #pragma unroll
    for (int p = 0; p < 4; ++p){              // stage h chunk transposed
      int idx = (p*256 + tid)*4;              // 0..4095
      int r = idx >> 6, c = idx & 63;
      float4 hv = make_float4(0.f,0.f,0.f,0.f);
      int row = row0 + r;
      if (row < N_NODES) hv = *(const float4*)&h[(size_t)row*128 + kc*64 + c];
      hTl[(c+0)*68 + r] = hv.x;
      hTl[(c+1)*68 + r] = hv.y;
      hTl[(c+2)*68 + r] = hv.z;
      hTl[(c+3)*68 + r] = hv.w;
    }
    __syncthreads();
    #pragma unroll 8
    for (int k = 0; k < 64; ++k){
      float4 hv = *(const float4*)&hTl[k*68 + ty*4];
      float4 wv = *(const float4*)&Wl [k*64 + tx*4];
      acc[0][0] += hv.x*wv.x; acc[0][1] += hv.x*wv.y; acc[0][2] += hv.x*wv.z; acc[0][3] += hv.x*wv.w;
      acc[1][0] += hv.y*wv.x; acc[1][1] += hv.y*wv.y; acc[1][2] += hv.y*wv.z; acc[1][3] += hv.y*wv.w;
      acc[2][0] += hv.z*wv.x; acc[2][1] += hv.z*wv.y; acc[2][2] += hv.z*wv.z; acc[2][3] += hv.z*wv.w;
      acc[3][0] += hv.w*wv.x; acc[3][1] += hv.w*wv.y; acc[3][2] += hv.w*wv.z; acc[3][3] += hv.w*wv.w;
    }
    __syncthreads();
  }
  #pragma unroll
  for (int i = 0; i < 4; ++i){
    int row = row0 + ty*4 + i;
    if (row < N_NODES)
      *(float4*)&feat[(size_t)row*HF + col0 + tx*4] =
        make_float4(acc[i][0], acc[i][1], acc[i][2], acc[i][3]);
  }
}

// ---------------- attention logits el/er per (node, head) ----------------
template<int F>
__global__ void k_el(const float* __restrict__ feat, const float* __restrict__ al,
                     const float* __restrict__ ar, float* __restrict__ el,
                     float* __restrict__ er){
  int t = blockIdx.x*256 + threadIdx.x;
  if (t >= N_NODES*4) return;
  int n = t >> 2, h = t & 3;
  const float* fp  = feat + (size_t)n*(4*F) + h*F;
  const float* alp = al + h*F;
  const float* arp = ar + h*F;
  float sl = 0.f, sr = 0.f;
  #pragma unroll
  for (int i = 0; i < F; i += 4){
    float4 f = *(const float4*)&fp[i];
    float4 a = *(const float4*)&alp[i];
    float4 b = *(const float4*)&arp[i];
    sl += f.x*a.x + f.y*a.y + f.z*a.z + f.w*a.w;
    sr += f.x*b.x + f.y*b.y + f.z*b.z + f.w*b.w;
  }
  el[t] = sl; er[t] = sr;
}

// ---------------- per-edge exp(lrelu(el[src]+er[dst])) in CSR order ----------------
__global__ void k_exp(const int* __restrict__ csr_src, const int* __restrict__ csr_dst,
                      const float* __restrict__ el, const float* __restrict__ er,
                      float* __restrict__ expv){
  int pos = blockIdx.x*256 + threadIdx.x;
  if (pos >= N_EDGES) return;
  int s = csr_src[pos], d = csr_dst[pos];
  float4 l4 = ((const float4*)el)[s];
  float4 r4 = ((const float4*)er)[d];
  float4 ex;
  ex.x = __expf(lrelu(l4.x + r4.x));
  ex.y = __expf(lrelu(l4.y + r4.y));
  ex.z = __expf(lrelu(l4.z + r4.z));
  ex.w = __expf(lrelu(l4.w + r4.w));
  ((float4*)expv)[pos] = ex;
}

// ---------------- per-dst-node softmax + aggregation (1 wave / node) ----------------
// F=32: two 32-lane halves each process a different edge with float4/lane (1KB/iter).
// F=64 FINAL: full wave per edge, float4/lane; head-mean epilogue.
template<int F, bool FINAL>
__global__ __launch_bounds__(256) void k_agg(const int* __restrict__ offs,
        const int* __restrict__ csr_src, const float* __restrict__ expv,
        const float* __restrict__ feat, const float* __restrict__ bias,
        float* __restrict__ out){
  int lane = threadIdx.x & 63;
  int n = (blockIdx.x*256 + threadIdx.x) >> 6;   // 12500 blocks * 4 waves = 50000 exactly
  if (n >= N_NODES) return;
  int beg = offs[n], end = offs[n+1];

  // pass A: softmax denominator per head (coalesced float4 reads of expv)
  float4 dsum = make_float4(0.f,0.f,0.f,0.f);
  for (int e = beg + lane; e < end; e += 64){
    float4 ex = ((const float4*)expv)[e];
    dsum.x += ex.x; dsum.y += ex.y; dsum.z += ex.z; dsum.w += ex.w;
  }
  #pragma unroll
  for (int m = 32; m >= 1; m >>= 1){
    dsum.x += __shfl_xor(dsum.x, m);
    dsum.y += __shfl_xor(dsum.y, m);
    dsum.z += __shfl_xor(dsum.z, m);
    dsum.w += __shfl_xor(dsum.w, m);
  }

  if (F == 32){
    int half = lane >> 5;        // which edge of the pair
    int l5   = lane & 31;        // feature slot: floats l5*4..l5*4+3 of 128
    int h    = l5 >> 3;
    float den = (h==0) ? dsum.x : (h==1) ? dsum.y : (h==2) ? dsum.z : dsum.w;
    float rden = 1.f / fmaxf(den, 1e-9f);
    float a0=0.f, a1=0.f, a2=0.f, a3=0.f;
    #pragma unroll 2
    for (int base = beg; base < end; base += 2){
      int e = base + half;
      if (e < end){
        int s = csr_src[e];
        float ev = expv[(size_t)e*4 + h];
        float4 v = *(const float4*)&feat[(size_t)s*128 + l5*4];
        a0 += ev*v.x; a1 += ev*v.y; a2 += ev*v.z; a3 += ev*v.w;
      }
    }
    a0 += __shfl_xor(a0, 32);
    a1 += __shfl_xor(a1, 32);
    a2 += __shfl_xor(a2, 32);
    a3 += __shfl_xor(a3, 32);
    if (half == 0){
      float4 o;
      o.x = eluf(a0*rden + bias[l5*4+0]);
      o.y = eluf(a1*rden + bias[l5*4+1]);
      o.z = eluf(a2*rden + bias[l5*4+2]);
      o.w = eluf(a3*rden + bias[l5*4+3]);
      *(float4*)&out[(size_t)n*128 + l5*4] = o;
    }
  } else {
    int h = lane >> 4;
    float den = (h==0) ? dsum.x : (h==1) ? dsum.y : (h==2) ? dsum.z : dsum.w;
    float rden = 1.f / fmaxf(den, 1e-9f);
    float a0=0.f, a1=0.f, a2=0.f, a3=0.f;
    #pragma unroll 2
    for (int e = beg; e < end; ++e){
      int s = csr_src[e];
      float ev = expv[(size_t)e*4 + h];
      float4 v = *(const float4*)&feat[(size_t)s*256 + lane*4];
      a0 += ev*v.x; a1 += ev*v.y; a2 += ev*v.z; a3 += ev*v.w;
    }
    float v0 = a0*rden + bias[lane*4+0];
    float v1 = a1*rden + bias[lane*4+1];
    float v2 = a2*rden + bias[lane*4+2];
    float v3 = a3*rden + bias[lane*4+3];
    // mean over heads: combine lanes with equal (lane & 15)
    v0 += __shfl_xor(v0, 16); v0 += __shfl_xor(v0, 32);
    v1 += __shfl_xor(v1, 16); v1 += __shfl_xor(v1, 32);
    v2 += __shfl_xor(v2, 16); v2 += __shfl_xor(v2, 32);
    v3 += __shfl_xor(v3, 16); v3 += __shfl_xor(v3, 32);
    if (lane < 16)
      *(float4*)&out[(size_t)n*64 + lane*4] =
        make_float4(v0*0.25f, v1*0.25f, v2*0.25f, v3*0.25f);
  }
}

extern "C" void kernel_launch(void* const* d_in, const int* in_sizes, int n_in,
                              void* d_out, int out_size, void* d_ws, size_t ws_size,
                              hipStream_t stream){
  const float* x   = (const float*)d_in[0];
  const int*   src = (const int*)  d_in[1];
  const int*   dst = (const int*)  d_in[2];
  const float* W[4]  = {(const float*)d_in[3],  (const float*)d_in[7],
                        (const float*)d_in[11], (const float*)d_in[15]};
  const float* al[4] = {(const float*)d_in[4],  (const float*)d_in[8],
                        (const float*)d_in[12], (const float*)d_in[16]};
  const float* ar[4] = {(const float*)d_in[5],  (const float*)d_in[9],
                        (const float*)d_in[13], (const float*)d_in[17]};
  const float* b[4]  = {(const float*)d_in[6],  (const float*)d_in[10],
                        (const float*)d_in[14], (const float*)d_in[18]};

  char* ws = (char*)d_ws;
  float* bufH    = (float*)(ws);                  // 25,600,000
  float* feat    = (float*)(ws + 25600000);       // 51,200,000
  float* el      = (float*)(ws + 76800000);       // 800,000
  float* er      = (float*)(ws + 77600000);       // 800,000
  int*   offs    = (int*)  (ws + 78400000);       // 200,004 (padded)
  int*   cur     = (int*)  (ws + 78600032);       // 200,000
  int*   bsum    = (int*)  (ws + 78800032);       // 1,024
  int*   csr_src = (int*)  (ws + 78801056);       // 3,200,000
  int*   csr_dst = (int*)  (ws + 82001056);       // 3,200,000
  float* expv    = (float*)(ws + 85201056);       // 12,800,000   (end ~98 MB)

  // ---- CSR build (per call; ws is re-poisoned) ----
  hipMemsetAsync(cur, 0, N_NODES*sizeof(int), stream);
  k_hist   <<<3125, 256, 0, stream>>>(dst, cur);
  k_scan1  <<<196,  256, 0, stream>>>(cur, offs, bsum);
  k_scan2  <<<1,    256, 0, stream>>>(bsum, 196);
  k_scan3  <<<196,  256, 0, stream>>>(offs, bsum, cur);
  k_scatter<<<3125, 256, 0, stream>>>(src, dst, cur, csr_src, csr_dst);

  // ---- layers 1..3 (HF=128, F=32) ----
  const float* hin = x;
  for (int l = 0; l < 3; ++l){
    k_gemm<128><<<dim3(782,2), 256, 0, stream>>>(hin, W[l], feat);
    k_el<32>   <<<782, 256, 0, stream>>>(feat, al[l], ar[l], el, er);
    k_exp      <<<3125, 256, 0, stream>>>(csr_src, csr_dst, el, er, expv);
    k_agg<32,false><<<12500, 256, 0, stream>>>(offs, csr_src, expv, feat, b[l], bufH);
    hin = bufH;
  }
  // ---- layer 4 (HF=256, F=64) + head-mean ----
  k_gemm<256><<<dim3(782,4), 256, 0, stream>>>(bufH, W[3], feat);
  k_el<64>   <<<782, 256, 0, stream>>>(feat, al[3], ar[3], el, er);
  k_exp      <<<3125, 256, 0, stream>>>(csr_src, csr_dst, el, er, expv);
  k_agg<64,true><<<12500, 256, 0, stream>>>(offs, csr_src, expv, feat, b[3], (float*)d_out);
}

// Round 3
// 712.290 us; speedup vs baseline: 1.1257x; 1.0228x over previous
//
#include <hip/hip_runtime.h>

#define N_NODES 50000
#define N_EDGES 800000

__device__ __forceinline__ float lrelu(float x){ return x > 0.f ? x : 0.2f*x; }
__device__ __forceinline__ float eluf (float x){ return x > 0.f ? x : __expf(x)-1.f; }

// ---------------- CSR build ----------------
__global__ void k_hist(const int* __restrict__ dst, int* __restrict__ cnt){
  int e = blockIdx.x*256 + threadIdx.x;
  if (e < N_EDGES) atomicAdd(&cnt[dst[e]], 1);
}

__global__ void k_scan1(const int* __restrict__ cnt, int* __restrict__ offs, int* __restrict__ bsum){
  __shared__ int tmp[256];
  int tid = threadIdx.x; int i = blockIdx.x*256 + tid;
  int v = (i < N_NODES) ? cnt[i] : 0;
  tmp[tid] = v; __syncthreads();
  for (int d = 1; d < 256; d <<= 1){
    int t = (tid >= d) ? tmp[tid-d] : 0;
    __syncthreads();
    tmp[tid] += t;
    __syncthreads();
  }
  if (i < N_NODES) offs[i] = tmp[tid] - v;          // exclusive within chunk
  if (tid == 255) bsum[blockIdx.x] = tmp[tid];       // chunk total
}

__global__ void k_scan2(int* __restrict__ bsum, int nb){
  __shared__ int tmp[256];
  int tid = threadIdx.x;
  int v = (tid < nb) ? bsum[tid] : 0;
  tmp[tid] = v; __syncthreads();
  for (int d = 1; d < 256; d <<= 1){
    int t = (tid >= d) ? tmp[tid-d] : 0;
    __syncthreads();
    tmp[tid] += t;
    __syncthreads();
  }
  if (tid < nb) bsum[tid] = tmp[tid] - v;            // exclusive chunk offsets
}

__global__ void k_scan3(int* __restrict__ offs, const int* __restrict__ bsum, int* __restrict__ cur){
  int i = blockIdx.x*256 + threadIdx.x;
  if (i < N_NODES){
    int o = offs[i] + bsum[blockIdx.x];
    offs[i] = o; cur[i] = o;
  }
  if (i == 0) offs[N_NODES] = N_EDGES;
}

__global__ void k_scatter(const int* __restrict__ src, const int* __restrict__ dst,
                          int* __restrict__ cur, int* __restrict__ csr_src,
                          int* __restrict__ csr_dst){
  int e = blockIdx.x*256 + threadIdx.x;
  if (e < N_EDGES){
    int d = dst[e];
    int pos = atomicAdd(&cur[d], 1);
    csr_src[pos] = src[e];
    csr_dst[pos] = d;
  }
}

// ---------------- GEMM: feat[N,HF] = h[N,128] @ W[128,HF] ----------------
template<int HF>
__global__ __launch_bounds__(256) void k_gemm(const float* __restrict__ h,
                                              const float* __restrict__ W,
                                              float* __restrict__ feat){
  __shared__ float Wl[64*64];    // [k][j]
  __shared__ float hTl[64*68];   // [k][r], pad 68 breaks transpose-store conflicts
  int tid = threadIdx.x;
  int tx = tid & 15, ty = tid >> 4;
  int row0 = blockIdx.x * 64;
  int col0 = blockIdx.y * 64;
  float acc[4][4] = {};
  for (int kc = 0; kc < 2; ++kc){
    #pragma unroll
    for (int p = 0; p < 4; ++p){              // stage W chunk [64k x 64j]
      int k = p*16 + ty;
      float4 wv = *(const float4*)&W[(size_t)(kc*64 + k)*HF + col0 + tx*4];
      *(float4*)&Wl[k*64 + tx*4] = wv;
    }
    #pragma unroll
    for (int p = 0; p < 4; ++p){              // stage h chunk transposed
      int idx = (p*256 + tid)*4;              // 0..4095
      int r = idx >> 6, c = idx & 63;
      float4 hv = make_float4(0.f,0.f,0.f,0.f);
      int row = row0 + r;
      if (row < N_NODES) hv = *(const float4*)&h[(size_t)row*128 + kc*64 + c];
      hTl[(c+0)*68 + r] = hv.x;
      hTl[(c+1)*68 + r] = hv.y;
      hTl[(c+2)*68 + r] = hv.z;
      hTl[(c+3)*68 + r] = hv.w;
    }
    __syncthreads();
    #pragma unroll 8
    for (int k = 0; k < 64; ++k){
      float4 hv = *(const float4*)&hTl[k*68 + ty*4];
      float4 wv = *(const float4*)&Wl [k*64 + tx*4];
      acc[0][0] += hv.x*wv.x; acc[0][1] += hv.x*wv.y; acc[0][2] += hv.x*wv.z; acc[0][3] += hv.x*wv.w;
      acc[1][0] += hv.y*wv.x; acc[1][1] += hv.y*wv.y; acc[1][2] += hv.y*wv.z; acc[1][3] += hv.y*wv.w;
      acc[2][0] += hv.z*wv.x; acc[2][1] += hv.z*wv.y; acc[2][2] += hv.z*wv.z; acc[2][3] += hv.z*wv.w;
      acc[3][0] += hv.w*wv.x; acc[3][1] += hv.w*wv.y; acc[3][2] += hv.w*wv.z; acc[3][3] += hv.w*wv.w;
    }
    __syncthreads();
  }
  #pragma unroll
  for (int i = 0; i < 4; ++i){
    int row = row0 + ty*4 + i;
    if (row < N_NODES)
      *(float4*)&feat[(size_t)row*HF + col0 + tx*4] =
        make_float4(acc[i][0], acc[i][1], acc[i][2], acc[i][3]);
  }
}

// ---------------- attention logits el/er per (node, head) ----------------
template<int F>
__global__ void k_el(const float* __restrict__ feat, const float* __restrict__ al,
                     const float* __restrict__ ar, float* __restrict__ el,
                     float* __restrict__ er){
  int t = blockIdx.x*256 + threadIdx.x;
  if (t >= N_NODES*4) return;
  int n = t >> 2, h = t & 3;
  const float* fp  = feat + (size_t)n*(4*F) + h*F;
  const float* alp = al + h*F;
  const float* arp = ar + h*F;
  float sl = 0.f, sr = 0.f;
  #pragma unroll
  for (int i = 0; i < F; i += 4){
    float4 f = *(const float4*)&fp[i];
    float4 a = *(const float4*)&alp[i];
    float4 b = *(const float4*)&arp[i];
    sl += f.x*a.x + f.y*a.y + f.z*a.z + f.w*a.w;
    sr += f.x*b.x + f.y*b.y + f.z*b.z + f.w*b.w;
  }
  el[t] = sl; er[t] = sr;
}

// ---------------- per-edge exp(lrelu(el[src]+er[dst])) in CSR order ----------------
__global__ void k_exp(const int* __restrict__ csr_src, const int* __restrict__ csr_dst,
                      const float* __restrict__ el, const float* __restrict__ er,
                      float* __restrict__ expv){
  int pos = blockIdx.x*256 + threadIdx.x;
  if (pos >= N_EDGES) return;
  int s = csr_src[pos], d = csr_dst[pos];
  float4 l4 = ((const float4*)el)[s];
  float4 r4 = ((const float4*)er)[d];
  float4 ex;
  ex.x = __expf(lrelu(l4.x + r4.x));
  ex.y = __expf(lrelu(l4.y + r4.y));
  ex.z = __expf(lrelu(l4.z + r4.z));
  ex.w = __expf(lrelu(l4.w + r4.w));
  ((float4*)expv)[pos] = ex;
}

// ---------------- per-dst-node softmax + aggregation (1 wave / node) ----------------
// F=32: two 32-lane halves; batches of 8 edges/half with all gathers issued
// before any FMA (branch-free filler) to maximize memory-level parallelism.
// F=64 FINAL: full wave per edge, batches of 4 edges; head-mean epilogue.
template<int F, bool FINAL>
__global__ __launch_bounds__(256) void k_agg(const int* __restrict__ offs,
        const int* __restrict__ csr_src, const float* __restrict__ expv,
        const float* __restrict__ feat, const float* __restrict__ bias,
        float* __restrict__ out){
  int lane = threadIdx.x & 63;
  int n = (blockIdx.x*256 + threadIdx.x) >> 6;   // 12500 blocks * 4 waves = 50000 exactly
  if (n >= N_NODES) return;
  int beg = offs[n], end = offs[n+1];

  // pass A: softmax denominator per head (coalesced float4 reads of expv)
  float4 dsum = make_float4(0.f,0.f,0.f,0.f);
  for (int e = beg + lane; e < end; e += 64){
    float4 ex = ((const float4*)expv)[e];
    dsum.x += ex.x; dsum.y += ex.y; dsum.z += ex.z; dsum.w += ex.w;
  }
  #pragma unroll
  for (int m = 32; m >= 1; m >>= 1){
    dsum.x += __shfl_xor(dsum.x, m);
    dsum.y += __shfl_xor(dsum.y, m);
    dsum.z += __shfl_xor(dsum.z, m);
    dsum.w += __shfl_xor(dsum.w, m);
  }
  int sfill = (beg < end) ? beg : 0;   // safe filler edge (weight forced to 0)

  if (F == 32){
    int half = lane >> 5;        // which edge of the pair
    int l5   = lane & 31;        // feature slot: floats l5*4..l5*4+3 of 128
    int h    = l5 >> 3;
    float den = (h==0) ? dsum.x : (h==1) ? dsum.y : (h==2) ? dsum.z : dsum.w;
    float rden = 1.f / fmaxf(den, 1e-9f);
    float a0=0.f, a1=0.f, a2=0.f, a3=0.f;
    for (int base = beg; base < end; base += 16){   // 16 edges/batch, 8 per half
      int   ss[8]; float ev[8];
      #pragma unroll
      for (int i = 0; i < 8; ++i){
        int e = base + 2*i + half;
        bool ok = e < end;
        int  ee = ok ? e : sfill;
        ss[i] = csr_src[ee];
        ev[i] = ok ? expv[(size_t)e*4 + h] : 0.f;
      }
      float4 vv[8];
      #pragma unroll
      for (int i = 0; i < 8; ++i)
        vv[i] = *(const float4*)&feat[(size_t)ss[i]*128 + l5*4];
      #pragma unroll
      for (int i = 0; i < 8; ++i){
        a0 += ev[i]*vv[i].x; a1 += ev[i]*vv[i].y;
        a2 += ev[i]*vv[i].z; a3 += ev[i]*vv[i].w;
      }
    }
    a0 += __shfl_xor(a0, 32);
    a1 += __shfl_xor(a1, 32);
    a2 += __shfl_xor(a2, 32);
    a3 += __shfl_xor(a3, 32);
    if (half == 0){
      float4 bv = *(const float4*)&bias[l5*4];
      float4 o;
      o.x = eluf(a0*rden + bv.x);
      o.y = eluf(a1*rden + bv.y);
      o.z = eluf(a2*rden + bv.z);
      o.w = eluf(a3*rden + bv.w);
      *(float4*)&out[(size_t)n*128 + l5*4] = o;
    }
  } else {
    int h = lane >> 4;
    float den = (h==0) ? dsum.x : (h==1) ? dsum.y : (h==2) ? dsum.z : dsum.w;
    float rden = 1.f / fmaxf(den, 1e-9f);
    float a0=0.f, a1=0.f, a2=0.f, a3=0.f;
    for (int base = beg; base < end; base += 4){    // 4 edges/batch, full wave each
      int   ss[4]; float ev[4];
      #pragma unroll
      for (int i = 0; i < 4; ++i){
        int e = base + i;
        bool ok = e < end;
        int  ee = ok ? e : sfill;
        ss[i] = csr_src[ee];
        ev[i] = ok ? expv[(size_t)e*4 + h] : 0.f;
      }
      float4 vv[4];
      #pragma unroll
      for (int i = 0; i < 4; ++i)
        vv[i] = *(const float4*)&feat[(size_t)ss[i]*256 + lane*4];
      #pragma unroll
      for (int i = 0; i < 4; ++i){
        a0 += ev[i]*vv[i].x; a1 += ev[i]*vv[i].y;
        a2 += ev[i]*vv[i].z; a3 += ev[i]*vv[i].w;
      }
    }
    float4 bv = *(const float4*)&bias[lane*4];
    float v0 = a0*rden + bv.x;
    float v1 = a1*rden + bv.y;
    float v2 = a2*rden + bv.z;
    float v3 = a3*rden + bv.w;
    // mean over heads: combine lanes with equal (lane & 15)
    v0 += __shfl_xor(v0, 16); v0 += __shfl_xor(v0, 32);
    v1 += __shfl_xor(v1, 16); v1 += __shfl_xor(v1, 32);
    v2 += __shfl_xor(v2, 16); v2 += __shfl_xor(v2, 32);
    v3 += __shfl_xor(v3, 16); v3 += __shfl_xor(v3, 32);
    if (lane < 16)
      *(float4*)&out[(size_t)n*64 + lane*4] =
        make_float4(v0*0.25f, v1*0.25f, v2*0.25f, v3*0.25f);
  }
}

extern "C" void kernel_launch(void* const* d_in, const int* in_sizes, int n_in,
                              void* d_out, int out_size, void* d_ws, size_t ws_size,
                              hipStream_t stream){
  const float* x   = (const float*)d_in[0];
  const int*   src = (const int*)  d_in[1];
  const int*   dst = (const int*)  d_in[2];
  const float* W[4]  = {(const float*)d_in[3],  (const float*)d_in[7],
                        (const float*)d_in[11], (const float*)d_in[15]};
  const float* al[4] = {(const float*)d_in[4],  (const float*)d_in[8],
                        (const float*)d_in[12], (const float*)d_in[16]};
  const float* ar[4] = {(const float*)d_in[5],  (const float*)d_in[9],
                        (const float*)d_in[13], (const float*)d_in[17]};
  const float* b[4]  = {(const float*)d_in[6],  (const float*)d_in[10],
                        (const float*)d_in[14], (const float*)d_in[18]};

  char* ws = (char*)d_ws;
  float* bufH    = (float*)(ws);                  // 25,600,000
  float* feat    = (float*)(ws + 25600000);       // 51,200,000
  float* el      = (float*)(ws + 76800000);       // 800,000
  float* er      = (float*)(ws + 77600000);       // 800,000
  int*   offs    = (int*)  (ws + 78400000);       // 200,004 (padded)
  int*   cur     = (int*)  (ws + 78600032);       // 200,000
  int*   bsum    = (int*)  (ws + 78800032);       // 1,024
  int*   csr_src = (int*)  (ws + 78801056);       // 3,200,000
  int*   csr_dst = (int*)  (ws + 82001056);       // 3,200,000
  float* expv    = (float*)(ws + 85201056);       // 12,800,000   (end ~98 MB)

  // ---- CSR build (per call; ws is re-poisoned) ----
  hipMemsetAsync(cur, 0, N_NODES*sizeof(int), stream);
  k_hist   <<<3125, 256, 0, stream>>>(dst, cur);
  k_scan1  <<<196,  256, 0, stream>>>(cur, offs, bsum);
  k_scan2  <<<1,    256, 0, stream>>>(bsum, 196);
  k_scan3  <<<196,  256, 0, stream>>>(offs, bsum, cur);
  k_scatter<<<3125, 256, 0, stream>>>(src, dst, cur, csr_src, csr_dst);

  // ---- layers 1..3 (HF=128, F=32) ----
  const float* hin = x;
  for (int l = 0; l < 3; ++l){
    k_gemm<128><<<dim3(782,2), 256, 0, stream>>>(hin, W[l], feat);
    k_el<32>   <<<782, 256, 0, stream>>>(feat, al[l], ar[l], el, er);
    k_exp      <<<3125, 256, 0, stream>>>(csr_src, csr_dst, el, er, expv);
    k_agg<32,false><<<12500, 256, 0, stream>>>(offs, csr_src, expv, feat, b[l], bufH);
    hin = bufH;
  }
  // ---- layer 4 (HF=256, F=64) + head-mean ----
  k_gemm<256><<<dim3(782,4), 256, 0, stream>>>(bufH, W[3], feat);
  k_el<64>   <<<782, 256, 0, stream>>>(feat, al[3], ar[3], el, er);
  k_exp      <<<3125, 256, 0, stream>>>(csr_src, csr_dst, el, er, expv);
  k_agg<64,true><<<12500, 256, 0, stream>>>(offs, csr_src, expv, feat, b[3], (float*)d_out);
}

// Round 4
// 674.840 us; speedup vs baseline: 1.1882x; 1.0555x over previous
//
#include <hip/hip_runtime.h>

#define N_NODES 50000
#define N_EDGES 800000

__device__ __forceinline__ float lrelu(float x){ return x > 0.f ? x : 0.2f*x; }
__device__ __forceinline__ float eluf (float x){ return x > 0.f ? x : __expf(x)-1.f; }

// ---------------- CSR build ----------------
__global__ void k_hist(const int* __restrict__ dst, int* __restrict__ cnt){
  int e = blockIdx.x*256 + threadIdx.x;
  if (e < N_EDGES) atomicAdd(&cnt[dst[e]], 1);
}

__global__ void k_scan1(const int* __restrict__ cnt, int* __restrict__ offs, int* __restrict__ bsum){
  __shared__ int tmp[256];
  int tid = threadIdx.x; int i = blockIdx.x*256 + tid;
  int v = (i < N_NODES) ? cnt[i] : 0;
  tmp[tid] = v; __syncthreads();
  for (int d = 1; d < 256; d <<= 1){
    int t = (tid >= d) ? tmp[tid-d] : 0;
    __syncthreads();
    tmp[tid] += t;
    __syncthreads();
  }
  if (i < N_NODES) offs[i] = tmp[tid] - v;          // exclusive within chunk
  if (tid == 255) bsum[blockIdx.x] = tmp[tid];       // chunk total
}

__global__ void k_scan2(int* __restrict__ bsum, int nb){
  __shared__ int tmp[256];
  int tid = threadIdx.x;
  int v = (tid < nb) ? bsum[tid] : 0;
  tmp[tid] = v; __syncthreads();
  for (int d = 1; d < 256; d <<= 1){
    int t = (tid >= d) ? tmp[tid-d] : 0;
    __syncthreads();
    tmp[tid] += t;
    __syncthreads();
  }
  if (tid < nb) bsum[tid] = tmp[tid] - v;            // exclusive chunk offsets
}

__global__ void k_scan3(int* __restrict__ offs, const int* __restrict__ bsum, int* __restrict__ cur){
  int i = blockIdx.x*256 + threadIdx.x;
  if (i < N_NODES){
    int o = offs[i] + bsum[blockIdx.x];
    offs[i] = o; cur[i] = o;
  }
  if (i == 0) offs[N_NODES] = N_EDGES;
}

__global__ void k_scatter(const int* __restrict__ src, const int* __restrict__ dst,
                          int* __restrict__ cur, int* __restrict__ csr_src,
                          int* __restrict__ csr_dst){
  int e = blockIdx.x*256 + threadIdx.x;
  if (e < N_EDGES){
    int d = dst[e];
    int pos = atomicAdd(&cur[d], 1);
    csr_src[pos] = src[e];
    csr_dst[pos] = d;
  }
}

// ---------------- GEMM: feat[N,HF] = h[N,128] @ W[128,HF], fused el/er ----------------
// Each 64-col window covers whole heads (F=32: 2 heads; F=64: 1 head), so el/er
// for (row, head) are computed entirely in-block: per-thread partial dot of its
// 4x4 acc with al/ar, shfl_xor reduce over the 8 (F=32) / 16 (F=64) tx-lanes of
// the head, single lane stores. No atomics, no separate k_el pass over feat.
template<int HF, int LAYER>
__global__ __launch_bounds__(256) void k_gemm(const float* __restrict__ h,
                                              const float* __restrict__ W,
                                              float* __restrict__ feat,
                                              const float* __restrict__ al,
                                              const float* __restrict__ ar,
                                              float* __restrict__ el,
                                              float* __restrict__ er){
  __shared__ float Wl[64*64];    // [k][j]
  __shared__ float hTl[64*68];   // [k][r], pad 68 breaks transpose-store conflicts
  int tid = threadIdx.x;
  int tx = tid & 15, ty = tid >> 4;
  int row0 = blockIdx.x * 64;
  int col0 = blockIdx.y * 64;
  float acc[4][4] = {};
  for (int kc = 0; kc < 2; ++kc){
    #pragma unroll
    for (int p = 0; p < 4; ++p){              // stage W chunk [64k x 64j]
      int k = p*16 + ty;
      float4 wv = *(const float4*)&W[(size_t)(kc*64 + k)*HF + col0 + tx*4];
      *(float4*)&Wl[k*64 + tx*4] = wv;
    }
    #pragma unroll
    for (int p = 0; p < 4; ++p){              // stage h chunk transposed
      int idx = (p*256 + tid)*4;              // 0..4095
      int r = idx >> 6, c = idx & 63;
      float4 hv = make_float4(0.f,0.f,0.f,0.f);
      int row = row0 + r;
      if (row < N_NODES) hv = *(const float4*)&h[(size_t)row*128 + kc*64 + c];
      hTl[(c+0)*68 + r] = hv.x;
      hTl[(c+1)*68 + r] = hv.y;
      hTl[(c+2)*68 + r] = hv.z;
      hTl[(c+3)*68 + r] = hv.w;
    }
    __syncthreads();
    #pragma unroll 8
    for (int k = 0; k < 64; ++k){
      float4 hv = *(const float4*)&hTl[k*68 + ty*4];
      float4 wv = *(const float4*)&Wl [k*64 + tx*4];
      acc[0][0] += hv.x*wv.x; acc[0][1] += hv.x*wv.y; acc[0][2] += hv.x*wv.z; acc[0][3] += hv.x*wv.w;
      acc[1][0] += hv.y*wv.x; acc[1][1] += hv.y*wv.y; acc[1][2] += hv.y*wv.z; acc[1][3] += hv.y*wv.w;
      acc[2][0] += hv.z*wv.x; acc[2][1] += hv.z*wv.y; acc[2][2] += hv.z*wv.z; acc[2][3] += hv.z*wv.w;
      acc[3][0] += hv.w*wv.x; acc[3][1] += hv.w*wv.y; acc[3][2] += hv.w*wv.z; acc[3][3] += hv.w*wv.w;
    }
    __syncthreads();
  }
  #pragma unroll
  for (int i = 0; i < 4; ++i){
    int row = row0 + ty*4 + i;
    if (row < N_NODES)
      *(float4*)&feat[(size_t)row*HF + col0 + tx*4] =
        make_float4(acc[i][0], acc[i][1], acc[i][2], acc[i][3]);
  }
  // ---- fused el/er epilogue ----
  constexpr int F = HF/4;             // head dim
  constexpr int G = (F == 32) ? 8 : 16; // tx-lanes per head
  float4 alv = *(const float4*)&al[col0 + tx*4];  // al flat [H,F] == al[gc]
  float4 arv = *(const float4*)&ar[col0 + tx*4];
  int hidx = (col0 + tx*4) / F;
  #pragma unroll
  for (int i = 0; i < 4; ++i){
    float pl = acc[i][0]*alv.x + acc[i][1]*alv.y + acc[i][2]*alv.z + acc[i][3]*alv.w;
    float pr = acc[i][0]*arv.x + acc[i][1]*arv.y + acc[i][2]*arv.z + acc[i][3]*arv.w;
    #pragma unroll
    for (int m = 1; m < G; m <<= 1){
      pl += __shfl_xor(pl, m);
      pr += __shfl_xor(pr, m);
    }
    int row = row0 + ty*4 + i;
    if ((tx & (G-1)) == 0 && row < N_NODES){
      el[row*4 + hidx] = pl;
      er[row*4 + hidx] = pr;
    }
  }
}

// ---------------- per-edge exp(lrelu(el[src]+er[dst])) in CSR order ----------------
__global__ void k_exp(const int* __restrict__ csr_src, const int* __restrict__ csr_dst,
                      const float* __restrict__ el, const float* __restrict__ er,
                      float* __restrict__ expv){
  int pos = blockIdx.x*256 + threadIdx.x;
  if (pos >= N_EDGES) return;
  int s = csr_src[pos], d = csr_dst[pos];
  float4 l4 = ((const float4*)el)[s];
  float4 r4 = ((const float4*)er)[d];
  float4 ex;
  ex.x = __expf(lrelu(l4.x + r4.x));
  ex.y = __expf(lrelu(l4.y + r4.y));
  ex.z = __expf(lrelu(l4.z + r4.z));
  ex.w = __expf(lrelu(l4.w + r4.w));
  ((float4*)expv)[pos] = ex;
}

// ---------------- per-dst-node softmax + aggregation (1 wave / node) ----------------
// R2 structure (best measured). F=32: two 32-lane halves, each a different edge,
// float4/lane (1KB per wave-instruction). F=64 FINAL: full wave per edge.
template<int F, bool FINAL, int LAYER>
__global__ __launch_bounds__(256) void k_agg(const int* __restrict__ offs,
        const int* __restrict__ csr_src, const float* __restrict__ expv,
        const float* __restrict__ feat, const float* __restrict__ bias,
        float* __restrict__ out){
  int lane = threadIdx.x & 63;
  int n = (blockIdx.x*256 + threadIdx.x) >> 6;   // 12500 blocks * 4 waves = 50000 exactly
  if (n >= N_NODES) return;
  int beg = offs[n], end = offs[n+1];

  // pass A: softmax denominator per head (coalesced float4 reads of expv)
  float4 dsum = make_float4(0.f,0.f,0.f,0.f);
  for (int e = beg + lane; e < end; e += 64){
    float4 ex = ((const float4*)expv)[e];
    dsum.x += ex.x; dsum.y += ex.y; dsum.z += ex.z; dsum.w += ex.w;
  }
  #pragma unroll
  for (int m = 32; m >= 1; m >>= 1){
    dsum.x += __shfl_xor(dsum.x, m);
    dsum.y += __shfl_xor(dsum.y, m);
    dsum.z += __shfl_xor(dsum.z, m);
    dsum.w += __shfl_xor(dsum.w, m);
  }

  if (F == 32){
    int half = lane >> 5;        // which edge of the pair
    int l5   = lane & 31;        // feature slot: floats l5*4..l5*4+3 of 128
    int h    = l5 >> 3;
    float den = (h==0) ? dsum.x : (h==1) ? dsum.y : (h==2) ? dsum.z : dsum.w;
    float rden = 1.f / fmaxf(den, 1e-9f);
    float a0=0.f, a1=0.f, a2=0.f, a3=0.f;
    #pragma unroll 2
    for (int base = beg; base < end; base += 2){
      int e = base + half;
      if (e < end){
        int s = csr_src[e];
        float ev = expv[(size_t)e*4 + h];
        float4 v = *(const float4*)&feat[(size_t)s*128 + l5*4];
        a0 += ev*v.x; a1 += ev*v.y; a2 += ev*v.z; a3 += ev*v.w;
      }
    }
    a0 += __shfl_xor(a0, 32);
    a1 += __shfl_xor(a1, 32);
    a2 += __shfl_xor(a2, 32);
    a3 += __shfl_xor(a3, 32);
    if (half == 0){
      float4 bv = *(const float4*)&bias[l5*4];
      float4 o;
      o.x = eluf(a0*rden + bv.x);
      o.y = eluf(a1*rden + bv.y);
      o.z = eluf(a2*rden + bv.z);
      o.w = eluf(a3*rden + bv.w);
      *(float4*)&out[(size_t)n*128 + l5*4] = o;
    }
  } else {
    int h = lane >> 4;
    float den = (h==0) ? dsum.x : (h==1) ? dsum.y : (h==2) ? dsum.z : dsum.w;
    float rden = 1.f / fmaxf(den, 1e-9f);
    float a0=0.f, a1=0.f, a2=0.f, a3=0.f;
    #pragma unroll 2
    for (int e = beg; e < end; ++e){
      int s = csr_src[e];
      float ev = expv[(size_t)e*4 + h];
      float4 v = *(const float4*)&feat[(size_t)s*256 + lane*4];
      a0 += ev*v.x; a1 += ev*v.y; a2 += ev*v.z; a3 += ev*v.w;
    }
    float4 bv = *(const float4*)&bias[lane*4];
    float v0 = a0*rden + bv.x;
    float v1 = a1*rden + bv.y;
    float v2 = a2*rden + bv.z;
    float v3 = a3*rden + bv.w;
    // mean over heads: combine lanes with equal (lane & 15)
    v0 += __shfl_xor(v0, 16); v0 += __shfl_xor(v0, 32);
    v1 += __shfl_xor(v1, 16); v1 += __shfl_xor(v1, 32);
    v2 += __shfl_xor(v2, 16); v2 += __shfl_xor(v2, 32);
    v3 += __shfl_xor(v3, 16); v3 += __shfl_xor(v3, 32);
    if (lane < 16)
      *(float4*)&out[(size_t)n*64 + lane*4] =
        make_float4(v0*0.25f, v1*0.25f, v2*0.25f, v3*0.25f);
  }
}

extern "C" void kernel_launch(void* const* d_in, const int* in_sizes, int n_in,
                              void* d_out, int out_size, void* d_ws, size_t ws_size,
                              hipStream_t stream){
  const float* x   = (const float*)d_in[0];
  const int*   src = (const int*)  d_in[1];
  const int*   dst = (const int*)  d_in[2];
  const float* W[4]  = {(const float*)d_in[3],  (const float*)d_in[7],
                        (const float*)d_in[11], (const float*)d_in[15]};
  const float* al[4] = {(const float*)d_in[4],  (const float*)d_in[8],
                        (const float*)d_in[12], (const float*)d_in[16]};
  const float* ar[4] = {(const float*)d_in[5],  (const float*)d_in[9],
                        (const float*)d_in[13], (const float*)d_in[17]};
  const float* b[4]  = {(const float*)d_in[6],  (const float*)d_in[10],
                        (const float*)d_in[14], (const float*)d_in[18]};

  char* ws = (char*)d_ws;
  float* bufH    = (float*)(ws);                  // 25,600,000
  float* feat    = (float*)(ws + 25600000);       // 51,200,000
  float* el      = (float*)(ws + 76800000);       // 800,000
  float* er      = (float*)(ws + 77600000);       // 800,000
  int*   offs    = (int*)  (ws + 78400000);       // 200,004 (padded)
  int*   cur     = (int*)  (ws + 78600032);       // 200,000
  int*   bsum    = (int*)  (ws + 78800032);       // 1,024
  int*   csr_src = (int*)  (ws + 78801056);       // 3,200,000
  int*   csr_dst = (int*)  (ws + 82001056);       // 3,200,000
  float* expv    = (float*)(ws + 85201056);       // 12,800,000   (end ~98 MB)

  // ---- CSR build (per call; ws is re-poisoned) ----
  hipMemsetAsync(cur, 0, N_NODES*sizeof(int), stream);
  k_hist   <<<3125, 256, 0, stream>>>(dst, cur);
  k_scan1  <<<196,  256, 0, stream>>>(cur, offs, bsum);
  k_scan2  <<<1,    256, 0, stream>>>(bsum, 196);
  k_scan3  <<<196,  256, 0, stream>>>(offs, bsum, cur);
  k_scatter<<<3125, 256, 0, stream>>>(src, dst, cur, csr_src, csr_dst);

  // ---- layer 1..3 (HF=128, F=32) ----
  k_gemm<128,1><<<dim3(782,2), 256, 0, stream>>>(x, W[0], feat, al[0], ar[0], el, er);
  k_exp        <<<3125, 256, 0, stream>>>(csr_src, csr_dst, el, er, expv);
  k_agg<32,false,1><<<12500, 256, 0, stream>>>(offs, csr_src, expv, feat, b[0], bufH);

  k_gemm<128,2><<<dim3(782,2), 256, 0, stream>>>(bufH, W[1], feat, al[1], ar[1], el, er);
  k_exp        <<<3125, 256, 0, stream>>>(csr_src, csr_dst, el, er, expv);
  k_agg<32,false,2><<<12500, 256, 0, stream>>>(offs, csr_src, expv, feat, b[1], bufH);

  k_gemm<128,3><<<dim3(782,2), 256, 0, stream>>>(bufH, W[2], feat, al[2], ar[2], el, er);
  k_exp        <<<3125, 256, 0, stream>>>(csr_src, csr_dst, el, er, expv);
  k_agg<32,false,3><<<12500, 256, 0, stream>>>(offs, csr_src, expv, feat, b[2], bufH);

  // ---- layer 4 (HF=256, F=64) + head-mean ----
  k_gemm<256,4><<<dim3(782,4), 256, 0, stream>>>(bufH, W[3], feat, al[3], ar[3], el, er);
  k_exp        <<<3125, 256, 0, stream>>>(csr_src, csr_dst, el, er, expv);
  k_agg<64,true,4><<<12500, 256, 0, stream>>>(offs, csr_src, expv, feat, b[3], (float*)d_out);
}

// Round 5
// 671.825 us; speedup vs baseline: 1.1936x; 1.0045x over previous
//
#include <hip/hip_runtime.h>

#define N_NODES 50000
#define N_EDGES 800000

__device__ __forceinline__ float lrelu(float x){ return x > 0.f ? x : 0.2f*x; }
__device__ __forceinline__ float eluf (float x){ return x > 0.f ? x : __expf(x)-1.f; }

// ---------------- CSR build ----------------
__global__ void k_hist(const int* __restrict__ dst, int* __restrict__ cnt){
  int e = blockIdx.x*256 + threadIdx.x;
  if (e < N_EDGES) atomicAdd(&cnt[dst[e]], 1);
}

__global__ void k_scan1(const int* __restrict__ cnt, int* __restrict__ offs, int* __restrict__ bsum){
  __shared__ int tmp[256];
  int tid = threadIdx.x; int i = blockIdx.x*256 + tid;
  int v = (i < N_NODES) ? cnt[i] : 0;
  tmp[tid] = v; __syncthreads();
  for (int d = 1; d < 256; d <<= 1){
    int t = (tid >= d) ? tmp[tid-d] : 0;
    __syncthreads();
    tmp[tid] += t;
    __syncthreads();
  }
  if (i < N_NODES) offs[i] = tmp[tid] - v;          // exclusive within chunk
  if (tid == 255) bsum[blockIdx.x] = tmp[tid];       // chunk total
}

__global__ void k_scan2(int* __restrict__ bsum, int nb){
  __shared__ int tmp[256];
  int tid = threadIdx.x;
  int v = (tid < nb) ? bsum[tid] : 0;
  tmp[tid] = v; __syncthreads();
  for (int d = 1; d < 256; d <<= 1){
    int t = (tid >= d) ? tmp[tid-d] : 0;
    __syncthreads();
    tmp[tid] += t;
    __syncthreads();
  }
  if (tid < nb) bsum[tid] = tmp[tid] - v;            // exclusive chunk offsets
}

__global__ void k_scan3(int* __restrict__ offs, const int* __restrict__ bsum, int* __restrict__ cur){
  int i = blockIdx.x*256 + threadIdx.x;
  if (i < N_NODES){
    int o = offs[i] + bsum[blockIdx.x];
    offs[i] = o; cur[i] = o;
  }
  if (i == 0) offs[N_NODES] = N_EDGES;
}

__global__ void k_scatter(const int* __restrict__ src, const int* __restrict__ dst,
                          int* __restrict__ cur, int* __restrict__ csr_src,
                          int* __restrict__ csr_dst){
  int e = blockIdx.x*256 + threadIdx.x;
  if (e < N_EDGES){
    int d = dst[e];
    int pos = atomicAdd(&cur[d], 1);
    csr_src[pos] = src[e];
    csr_dst[pos] = d;
  }
}

// ---------------- GEMM: feat[N,HF] = h[N,128] @ W[128,HF], fused el/er ----------------
template<int HF, int LAYER>
__global__ __launch_bounds__(256) void k_gemm(const float* __restrict__ h,
                                              const float* __restrict__ W,
                                              float* __restrict__ feat,
                                              const float* __restrict__ al,
                                              const float* __restrict__ ar,
                                              float* __restrict__ el,
                                              float* __restrict__ er){
  __shared__ float Wl[64*64];    // [k][j]
  __shared__ float hTl[64*68];   // [k][r], pad 68 breaks transpose-store conflicts
  int tid = threadIdx.x;
  int tx = tid & 15, ty = tid >> 4;
  int row0 = blockIdx.x * 64;
  int col0 = blockIdx.y * 64;
  float acc[4][4] = {};
  for (int kc = 0; kc < 2; ++kc){
    #pragma unroll
    for (int p = 0; p < 4; ++p){              // stage W chunk [64k x 64j]
      int k = p*16 + ty;
      float4 wv = *(const float4*)&W[(size_t)(kc*64 + k)*HF + col0 + tx*4];
      *(float4*)&Wl[k*64 + tx*4] = wv;
    }
    #pragma unroll
    for (int p = 0; p < 4; ++p){              // stage h chunk transposed
      int idx = (p*256 + tid)*4;              // 0..4095
      int r = idx >> 6, c = idx & 63;
      float4 hv = make_float4(0.f,0.f,0.f,0.f);
      int row = row0 + r;
      if (row < N_NODES) hv = *(const float4*)&h[(size_t)row*128 + kc*64 + c];
      hTl[(c+0)*68 + r] = hv.x;
      hTl[(c+1)*68 + r] = hv.y;
      hTl[(c+2)*68 + r] = hv.z;
      hTl[(c+3)*68 + r] = hv.w;
    }
    __syncthreads();
    #pragma unroll 8
    for (int k = 0; k < 64; ++k){
      float4 hv = *(const float4*)&hTl[k*68 + ty*4];
      float4 wv = *(const float4*)&Wl [k*64 + tx*4];
      acc[0][0] += hv.x*wv.x; acc[0][1] += hv.x*wv.y; acc[0][2] += hv.x*wv.z; acc[0][3] += hv.x*wv.w;
      acc[1][0] += hv.y*wv.x; acc[1][1] += hv.y*wv.y; acc[1][2] += hv.y*wv.z; acc[1][3] += hv.y*wv.w;
      acc[2][0] += hv.z*wv.x; acc[2][1] += hv.z*wv.y; acc[2][2] += hv.z*wv.z; acc[2][3] += hv.z*wv.w;
      acc[3][0] += hv.w*wv.x; acc[3][1] += hv.w*wv.y; acc[3][2] += hv.w*wv.z; acc[3][3] += hv.w*wv.w;
    }
    __syncthreads();
  }
  #pragma unroll
  for (int i = 0; i < 4; ++i){
    int row = row0 + ty*4 + i;
    if (row < N_NODES)
      *(float4*)&feat[(size_t)row*HF + col0 + tx*4] =
        make_float4(acc[i][0], acc[i][1], acc[i][2], acc[i][3]);
  }
  // ---- fused el/er epilogue ----
  constexpr int F = HF/4;               // head dim
  constexpr int G = (F == 32) ? 8 : 16; // tx-lanes per head
  float4 alv = *(const float4*)&al[col0 + tx*4];
  float4 arv = *(const float4*)&ar[col0 + tx*4];
  int hidx = (col0 + tx*4) / F;
  #pragma unroll
  for (int i = 0; i < 4; ++i){
    float pl = acc[i][0]*alv.x + acc[i][1]*alv.y + acc[i][2]*alv.z + acc[i][3]*alv.w;
    float pr = acc[i][0]*arv.x + acc[i][1]*arv.y + acc[i][2]*arv.z + acc[i][3]*arv.w;
    #pragma unroll
    for (int m = 1; m < G; m <<= 1){
      pl += __shfl_xor(pl, m);
      pr += __shfl_xor(pr, m);
    }
    int row = row0 + ty*4 + i;
    if ((tx & (G-1)) == 0 && row < N_NODES){
      el[row*4 + hidx] = pl;
      er[row*4 + hidx] = pr;
    }
  }
}

// ---------------- per-edge exp(lrelu(el[src]+er[dst])) in CSR order ----------------
__global__ void k_exp(const int* __restrict__ csr_src, const int* __restrict__ csr_dst,
                      const float* __restrict__ el, const float* __restrict__ er,
                      float* __restrict__ expv){
  int pos = blockIdx.x*256 + threadIdx.x;
  if (pos >= N_EDGES) return;
  int s = csr_src[pos], d = csr_dst[pos];
  float4 l4 = ((const float4*)el)[s];
  float4 r4 = ((const float4*)er)[d];
  float4 ex;
  ex.x = __expf(lrelu(l4.x + r4.x));
  ex.y = __expf(lrelu(l4.y + r4.y));
  ex.z = __expf(lrelu(l4.z + r4.z));
  ex.w = __expf(lrelu(l4.w + r4.w));
  ((float4*)expv)[pos] = ex;
}

// ---------------- per-dst-node softmax + aggregation (1 wave / node) ----------------
// MLP-batched: 4 independent float4 gathers in flight per wave iteration.
// __launch_bounds__(256,4) gives the allocator ~128-VGPR headroom so the 4
// gather results live in registers simultaneously (R3's version got squeezed
// to 28 VGPR and serialized). Filler edges clamp to a duplicate row (L2-hit).
template<int F, bool FINAL, int LAYER>
__global__ __launch_bounds__(256, 4) void k_agg(const int* __restrict__ offs,
        const int* __restrict__ csr_src, const float* __restrict__ expv,
        const float* __restrict__ feat, const float* __restrict__ bias,
        float* __restrict__ out){
  int lane = threadIdx.x & 63;
  int n = __builtin_amdgcn_readfirstlane((blockIdx.x*256 + threadIdx.x) >> 6);
  if (n >= N_NODES) return;
  int beg = offs[n], end = offs[n+1];

  // pass A: softmax denominator per head (coalesced float4 reads of expv)
  float4 dsum = make_float4(0.f,0.f,0.f,0.f);
  for (int e = beg + lane; e < end; e += 64){
    float4 ex = ((const float4*)expv)[e];
    dsum.x += ex.x; dsum.y += ex.y; dsum.z += ex.z; dsum.w += ex.w;
  }
  #pragma unroll
  for (int m = 32; m >= 1; m >>= 1){
    dsum.x += __shfl_xor(dsum.x, m);
    dsum.y += __shfl_xor(dsum.y, m);
    dsum.z += __shfl_xor(dsum.z, m);
    dsum.w += __shfl_xor(dsum.w, m);
  }

  if (F == 32){
    int half = lane >> 5;        // which edge of the pair
    int l5   = lane & 31;        // feature slot: floats l5*4..l5*4+3 of 128
    int h    = l5 >> 3;
    float den = (h==0) ? dsum.x : (h==1) ? dsum.y : (h==2) ? dsum.z : dsum.w;
    float rden = 1.f / fmaxf(den, 1e-9f);
    float a0=0.f, a1=0.f, a2=0.f, a3=0.f;
    for (int base = beg; base < end; base += 8){   // 8 edges/iter, 4 per half
      int   ss[4]; float ev[4];
      #pragma unroll
      for (int i = 0; i < 4; ++i){
        int e = base + 2*i + half;
        bool ok = e < end;
        int  ec = ok ? e : beg;
        ss[i] = csr_src[ec];
        ev[i] = ok ? expv[(size_t)e*4 + h] : 0.f;
      }
      float4 v0 = *(const float4*)&feat[(size_t)ss[0]*128 + l5*4];
      float4 v1 = *(const float4*)&feat[(size_t)ss[1]*128 + l5*4];
      float4 v2 = *(const float4*)&feat[(size_t)ss[2]*128 + l5*4];
      float4 v3 = *(const float4*)&feat[(size_t)ss[3]*128 + l5*4];
      a0 += ev[0]*v0.x; a1 += ev[0]*v0.y; a2 += ev[0]*v0.z; a3 += ev[0]*v0.w;
      a0 += ev[1]*v1.x; a1 += ev[1]*v1.y; a2 += ev[1]*v1.z; a3 += ev[1]*v1.w;
      a0 += ev[2]*v2.x; a1 += ev[2]*v2.y; a2 += ev[2]*v2.z; a3 += ev[2]*v2.w;
      a0 += ev[3]*v3.x; a1 += ev[3]*v3.y; a2 += ev[3]*v3.z; a3 += ev[3]*v3.w;
    }
    a0 += __shfl_xor(a0, 32);
    a1 += __shfl_xor(a1, 32);
    a2 += __shfl_xor(a2, 32);
    a3 += __shfl_xor(a3, 32);
    if (half == 0){
      float4 bv = *(const float4*)&bias[l5*4];
      float4 o;
      o.x = eluf(a0*rden + bv.x);
      o.y = eluf(a1*rden + bv.y);
      o.z = eluf(a2*rden + bv.z);
      o.w = eluf(a3*rden + bv.w);
      *(float4*)&out[(size_t)n*128 + l5*4] = o;
    }
  } else {
    int h = lane >> 4;
    float den = (h==0) ? dsum.x : (h==1) ? dsum.y : (h==2) ? dsum.z : dsum.w;
    float rden = 1.f / fmaxf(den, 1e-9f);
    float a0=0.f, a1=0.f, a2=0.f, a3=0.f;
    for (int base = beg; base < end; base += 4){    // 4 edges/batch, full wave each
      int   ss[4]; float ev[4];
      #pragma unroll
      for (int i = 0; i < 4; ++i){
        int e = base + i;
        bool ok = e < end;
        int  ec = ok ? e : beg;
        ss[i] = csr_src[ec];
        ev[i] = ok ? expv[(size_t)e*4 + h] : 0.f;
      }
      float4 v0 = *(const float4*)&feat[(size_t)ss[0]*256 + lane*4];
      float4 v1 = *(const float4*)&feat[(size_t)ss[1]*256 + lane*4];
      float4 v2 = *(const float4*)&feat[(size_t)ss[2]*256 + lane*4];
      float4 v3 = *(const float4*)&feat[(size_t)ss[3]*256 + lane*4];
      a0 += ev[0]*v0.x; a1 += ev[0]*v0.y; a2 += ev[0]*v0.z; a3 += ev[0]*v0.w;
      a0 += ev[1]*v1.x; a1 += ev[1]*v1.y; a2 += ev[1]*v1.z; a3 += ev[1]*v1.w;
      a0 += ev[2]*v2.x; a1 += ev[2]*v2.y; a2 += ev[2]*v2.z; a3 += ev[2]*v2.w;
      a0 += ev[3]*v3.x; a1 += ev[3]*v3.y; a2 += ev[3]*v3.z; a3 += ev[3]*v3.w;
    }
    float4 bv = *(const float4*)&bias[lane*4];
    float v0 = a0*rden + bv.x;
    float v1 = a1*rden + bv.y;
    float v2 = a2*rden + bv.z;
    float v3 = a3*rden + bv.w;
    // mean over heads: combine lanes with equal (lane & 15)
    v0 += __shfl_xor(v0, 16); v0 += __shfl_xor(v0, 32);
    v1 += __shfl_xor(v1, 16); v1 += __shfl_xor(v1, 32);
    v2 += __shfl_xor(v2, 16); v2 += __shfl_xor(v2, 32);
    v3 += __shfl_xor(v3, 16); v3 += __shfl_xor(v3, 32);
    if (lane < 16)
      *(float4*)&out[(size_t)n*64 + lane*4] =
        make_float4(v0*0.25f, v1*0.25f, v2*0.25f, v3*0.25f);
  }
}

extern "C" void kernel_launch(void* const* d_in, const int* in_sizes, int n_in,
                              void* d_out, int out_size, void* d_ws, size_t ws_size,
                              hipStream_t stream){
  const float* x   = (const float*)d_in[0];
  const int*   src = (const int*)  d_in[1];
  const int*   dst = (const int*)  d_in[2];
  const float* W[4]  = {(const float*)d_in[3],  (const float*)d_in[7],
                        (const float*)d_in[11], (const float*)d_in[15]};
  const float* al[4] = {(const float*)d_in[4],  (const float*)d_in[8],
                        (const float*)d_in[12], (const float*)d_in[16]};
  const float* ar[4] = {(const float*)d_in[5],  (const float*)d_in[9],
                        (const float*)d_in[13], (const float*)d_in[17]};
  const float* b[4]  = {(const float*)d_in[6],  (const float*)d_in[10],
                        (const float*)d_in[14], (const float*)d_in[18]};

  char* ws = (char*)d_ws;
  float* bufH    = (float*)(ws);                  // 25,600,000
  float* feat    = (float*)(ws + 25600000);       // 51,200,000
  float* el      = (float*)(ws + 76800000);       // 800,000
  float* er      = (float*)(ws + 77600000);       // 800,000
  int*   offs    = (int*)  (ws + 78400000);       // 200,004 (padded)
  int*   cur     = (int*)  (ws + 78600032);       // 200,000
  int*   bsum    = (int*)  (ws + 78800032);       // 1,024
  int*   csr_src = (int*)  (ws + 78801056);       // 3,200,000
  int*   csr_dst = (int*)  (ws + 82001056);       // 3,200,000
  float* expv    = (float*)(ws + 85201056);       // 12,800,000   (end ~98 MB)

  // ---- CSR build (per call; ws is re-poisoned) ----
  hipMemsetAsync(cur, 0, N_NODES*sizeof(int), stream);
  k_hist   <<<3125, 256, 0, stream>>>(dst, cur);
  k_scan1  <<<196,  256, 0, stream>>>(cur, offs, bsum);
  k_scan2  <<<1,    256, 0, stream>>>(bsum, 196);
  k_scan3  <<<196,  256, 0, stream>>>(offs, bsum, cur);
  k_scatter<<<3125, 256, 0, stream>>>(src, dst, cur, csr_src, csr_dst);

  // ---- layer 1..3 (HF=128, F=32) ----
  k_gemm<128,1><<<dim3(782,2), 256, 0, stream>>>(x, W[0], feat, al[0], ar[0], el, er);
  k_exp        <<<3125, 256, 0, stream>>>(csr_src, csr_dst, el, er, expv);
  k_agg<32,false,1><<<12500, 256, 0, stream>>>(offs, csr_src, expv, feat, b[0], bufH);

  k_gemm<128,2><<<dim3(782,2), 256, 0, stream>>>(bufH, W[1], feat, al[1], ar[1], el, er);
  k_exp        <<<3125, 256, 0, stream>>>(csr_src, csr_dst, el, er, expv);
  k_agg<32,false,2><<<12500, 256, 0, stream>>>(offs, csr_src, expv, feat, b[1], bufH);

  k_gemm<128,3><<<dim3(782,2), 256, 0, stream>>>(bufH, W[2], feat, al[2], ar[2], el, er);
  k_exp        <<<3125, 256, 0, stream>>>(csr_src, csr_dst, el, er, expv);
  k_agg<32,false,3><<<12500, 256, 0, stream>>>(offs, csr_src, expv, feat, b[2], bufH);

  // ---- layer 4 (HF=256, F=64) + head-mean ----
  k_gemm<256,4><<<dim3(782,4), 256, 0, stream>>>(bufH, W[3], feat, al[3], ar[3], el, er);
  k_exp        <<<3125, 256, 0, stream>>>(csr_src, csr_dst, el, er, expv);
  k_agg<64,true,4><<<12500, 256, 0, stream>>>(offs, csr_src, expv, feat, b[3], (float*)d_out);
}

// Round 7
// 669.525 us; speedup vs baseline: 1.1977x; 1.0034x over previous
//
#include <hip/hip_runtime.h>

#define N_NODES 50000
#define N_EDGES 800000

__device__ __forceinline__ float lrelu(float x){ return x > 0.f ? x : 0.2f*x; }
__device__ __forceinline__ float eluf (float x){ return x > 0.f ? x : __expf(x)-1.f; }

// Four independent gathers issued back-to-back inside ONE asm block, then a
// single vmcnt(0) drain. Early-clobber outputs ("=&v") prevent dest/addr
// aliasing; no tied operands (gfx950 backend rejects "+v" on vector tuples).
__device__ __forceinline__ void gather4(const float* p0, const float* p1,
                                        const float* p2, const float* p3,
                                        float4& v0, float4& v1,
                                        float4& v2, float4& v3){
  asm volatile("global_load_dwordx4 %0, %4, off\n\t"
               "global_load_dwordx4 %1, %5, off\n\t"
               "global_load_dwordx4 %2, %6, off\n\t"
               "global_load_dwordx4 %3, %7, off\n\t"
               "s_waitcnt vmcnt(0)"
               : "=&v"(v0), "=&v"(v1), "=&v"(v2), "=&v"(v3)
               : "v"(p0), "v"(p1), "v"(p2), "v"(p3));
}

// ---------------- CSR build ----------------
__global__ void k_hist(const int* __restrict__ dst, int* __restrict__ cnt){
  int e = blockIdx.x*256 + threadIdx.x;
  if (e < N_EDGES) atomicAdd(&cnt[dst[e]], 1);
}

__global__ void k_scan1(const int* __restrict__ cnt, int* __restrict__ offs, int* __restrict__ bsum){
  __shared__ int tmp[256];
  int tid = threadIdx.x; int i = blockIdx.x*256 + tid;
  int v = (i < N_NODES) ? cnt[i] : 0;
  tmp[tid] = v; __syncthreads();
  for (int d = 1; d < 256; d <<= 1){
    int t = (tid >= d) ? tmp[tid-d] : 0;
    __syncthreads();
    tmp[tid] += t;
    __syncthreads();
  }
  if (i < N_NODES) offs[i] = tmp[tid] - v;          // exclusive within chunk
  if (tid == 255) bsum[blockIdx.x] = tmp[tid];       // chunk total
}

__global__ void k_scan2(int* __restrict__ bsum, int nb){
  __shared__ int tmp[256];
  int tid = threadIdx.x;
  int v = (tid < nb) ? bsum[tid] : 0;
  tmp[tid] = v; __syncthreads();
  for (int d = 1; d < 256; d <<= 1){
    int t = (tid >= d) ? tmp[tid-d] : 0;
    __syncthreads();
    tmp[tid] += t;
    __syncthreads();
  }
  if (tid < nb) bsum[tid] = tmp[tid] - v;            // exclusive chunk offsets
}

__global__ void k_scan3(int* __restrict__ offs, const int* __restrict__ bsum, int* __restrict__ cur){
  int i = blockIdx.x*256 + threadIdx.x;
  if (i < N_NODES){
    int o = offs[i] + bsum[blockIdx.x];
    offs[i] = o; cur[i] = o;
  }
  if (i == 0) offs[N_NODES] = N_EDGES;
}

__global__ void k_scatter(const int* __restrict__ src, const int* __restrict__ dst,
                          int* __restrict__ cur, int* __restrict__ csr_src,
                          int* __restrict__ csr_dst){
  int e = blockIdx.x*256 + threadIdx.x;
  if (e < N_EDGES){
    int d = dst[e];
    int pos = atomicAdd(&cur[d], 1);
    csr_src[pos] = src[e];
    csr_dst[pos] = d;
  }
}

// ---------------- GEMM: feat[N,HF] = h[N,128] @ W[128,HF], fused el/er ----------------
template<int HF, int LAYER>
__global__ __launch_bounds__(256) void k_gemm(const float* __restrict__ h,
                                              const float* __restrict__ W,
                                              float* __restrict__ feat,
                                              const float* __restrict__ al,
                                              const float* __restrict__ ar,
                                              float* __restrict__ el,
                                              float* __restrict__ er){
  __shared__ float Wl[64*64];    // [k][j]
  __shared__ float hTl[64*68];   // [k][r], pad 68 breaks transpose-store conflicts
  int tid = threadIdx.x;
  int tx = tid & 15, ty = tid >> 4;
  int row0 = blockIdx.x * 64;
  int col0 = blockIdx.y * 64;
  float acc[4][4] = {};
  for (int kc = 0; kc < 2; ++kc){
    #pragma unroll
    for (int p = 0; p < 4; ++p){              // stage W chunk [64k x 64j]
      int k = p*16 + ty;
      float4 wv = *(const float4*)&W[(size_t)(kc*64 + k)*HF + col0 + tx*4];
      *(float4*)&Wl[k*64 + tx*4] = wv;
    }
    #pragma unroll
    for (int p = 0; p < 4; ++p){              // stage h chunk transposed
      int idx = (p*256 + tid)*4;              // 0..4095
      int r = idx >> 6, c = idx & 63;
      float4 hv = make_float4(0.f,0.f,0.f,0.f);
      int row = row0 + r;
      if (row < N_NODES) hv = *(const float4*)&h[(size_t)row*128 + kc*64 + c];
      hTl[(c+0)*68 + r] = hv.x;
      hTl[(c+1)*68 + r] = hv.y;
      hTl[(c+2)*68 + r] = hv.z;
      hTl[(c+3)*68 + r] = hv.w;
    }
    __syncthreads();
    #pragma unroll 8
    for (int k = 0; k < 64; ++k){
      float4 hv = *(const float4*)&hTl[k*68 + ty*4];
      float4 wv = *(const float4*)&Wl [k*64 + tx*4];
      acc[0][0] += hv.x*wv.x; acc[0][1] += hv.x*wv.y; acc[0][2] += hv.x*wv.z; acc[0][3] += hv.x*wv.w;
      acc[1][0] += hv.y*wv.x; acc[1][1] += hv.y*wv.y; acc[1][2] += hv.y*wv.z; acc[1][3] += hv.y*wv.w;
      acc[2][0] += hv.z*wv.x; acc[2][1] += hv.z*wv.y; acc[2][2] += hv.z*wv.z; acc[2][3] += hv.z*wv.w;
      acc[3][0] += hv.w*wv.x; acc[3][1] += hv.w*wv.y; acc[3][2] += hv.w*wv.z; acc[3][3] += hv.w*wv.w;
    }
    __syncthreads();
  }
  #pragma unroll
  for (int i = 0; i < 4; ++i){
    int row = row0 + ty*4 + i;
    if (row < N_NODES)
      *(float4*)&feat[(size_t)row*HF + col0 + tx*4] =
        make_float4(acc[i][0], acc[i][1], acc[i][2], acc[i][3]);
  }
  // ---- fused el/er epilogue ----
  constexpr int F = HF/4;               // head dim
  constexpr int G = (F == 32) ? 8 : 16; // tx-lanes per head
  float4 alv = *(const float4*)&al[col0 + tx*4];
  float4 arv = *(const float4*)&ar[col0 + tx*4];
  int hidx = (col0 + tx*4) / F;
  #pragma unroll
  for (int i = 0; i < 4; ++i){
    float pl = acc[i][0]*alv.x + acc[i][1]*alv.y + acc[i][2]*alv.z + acc[i][3]*alv.w;
    float pr = acc[i][0]*arv.x + acc[i][1]*arv.y + acc[i][2]*arv.z + acc[i][3]*arv.w;
    #pragma unroll
    for (int m = 1; m < G; m <<= 1){
      pl += __shfl_xor(pl, m);
      pr += __shfl_xor(pr, m);
    }
    int row = row0 + ty*4 + i;
    if ((tx & (G-1)) == 0 && row < N_NODES){
      el[row*4 + hidx] = pl;
      er[row*4 + hidx] = pr;
    }
  }
}

// ---------------- per-edge exp(lrelu(el[src]+er[dst])) in CSR order ----------------
__global__ void k_exp(const int* __restrict__ csr_src, const int* __restrict__ csr_dst,
                      const float* __restrict__ el, const float* __restrict__ er,
                      float* __restrict__ expv){
  int pos = blockIdx.x*256 + threadIdx.x;
  if (pos >= N_EDGES) return;
  int s = csr_src[pos], d = csr_dst[pos];
  float4 l4 = ((const float4*)el)[s];
  float4 r4 = ((const float4*)er)[d];
  float4 ex;
  ex.x = __expf(lrelu(l4.x + r4.x));
  ex.y = __expf(lrelu(l4.y + r4.y));
  ex.z = __expf(lrelu(l4.z + r4.z));
  ex.w = __expf(lrelu(l4.w + r4.w));
  ((float4*)expv)[pos] = ex;
}

// ---------------- per-dst-node softmax + aggregation (1 wave / node) ----------------
// MLP forced via the gather4 asm block: 4 independent global_load_dwordx4 in
// flight per iteration (compiler cannot split/serialize an asm body).
// Filler edges clamp to edge `beg` (dup row, L2-hit) with weight 0.
template<int F, bool FINAL, int LAYER>
__global__ __launch_bounds__(256, 4) void k_agg(const int* __restrict__ offs,
        const int* __restrict__ csr_src, const float* __restrict__ expv,
        const float* __restrict__ feat, const float* __restrict__ bias,
        float* __restrict__ out){
  int lane = threadIdx.x & 63;
  int n = __builtin_amdgcn_readfirstlane((blockIdx.x*256 + threadIdx.x) >> 6);
  if (n >= N_NODES) return;
  int beg = offs[n], end = offs[n+1];

  // pass A: softmax denominator per head (coalesced float4 reads of expv)
  float4 dsum = make_float4(0.f,0.f,0.f,0.f);
  for (int e = beg + lane; e < end; e += 64){
    float4 ex = ((const float4*)expv)[e];
    dsum.x += ex.x; dsum.y += ex.y; dsum.z += ex.z; dsum.w += ex.w;
  }
  #pragma unroll
  for (int m = 32; m >= 1; m >>= 1){
    dsum.x += __shfl_xor(dsum.x, m);
    dsum.y += __shfl_xor(dsum.y, m);
    dsum.z += __shfl_xor(dsum.z, m);
    dsum.w += __shfl_xor(dsum.w, m);
  }

  if (F == 32){
    int half = lane >> 5;        // which edge of the pair
    int l5   = lane & 31;        // feature slot: floats l5*4..l5*4+3 of 128
    int h    = l5 >> 3;
    float den = (h==0) ? dsum.x : (h==1) ? dsum.y : (h==2) ? dsum.z : dsum.w;
    float rden = 1.f / fmaxf(den, 1e-9f);
    float a0=0.f, a1=0.f, a2=0.f, a3=0.f;
    for (int base = beg; base < end; base += 8){   // 8 edges/iter, 4 per half
      int   ss[4]; float ev[4];
      #pragma unroll
      for (int i = 0; i < 4; ++i){
        int e = base + 2*i + half;
        bool ok = e < end;
        int  ec = ok ? e : beg;
        ss[i] = csr_src[ec];
        ev[i] = ok ? expv[(size_t)e*4 + h] : 0.f;
      }
      float4 v0, v1, v2, v3;
      gather4(&feat[(size_t)ss[0]*128 + l5*4], &feat[(size_t)ss[1]*128 + l5*4],
              &feat[(size_t)ss[2]*128 + l5*4], &feat[(size_t)ss[3]*128 + l5*4],
              v0, v1, v2, v3);
      a0 += ev[0]*v0.x; a1 += ev[0]*v0.y; a2 += ev[0]*v0.z; a3 += ev[0]*v0.w;
      a0 += ev[1]*v1.x; a1 += ev[1]*v1.y; a2 += ev[1]*v1.z; a3 += ev[1]*v1.w;
      a0 += ev[2]*v2.x; a1 += ev[2]*v2.y; a2 += ev[2]*v2.z; a3 += ev[2]*v2.w;
      a0 += ev[3]*v3.x; a1 += ev[3]*v3.y; a2 += ev[3]*v3.z; a3 += ev[3]*v3.w;
    }
    a0 += __shfl_xor(a0, 32);
    a1 += __shfl_xor(a1, 32);
    a2 += __shfl_xor(a2, 32);
    a3 += __shfl_xor(a3, 32);
    if (half == 0){
      float4 bv = *(const float4*)&bias[l5*4];
      float4 o;
      o.x = eluf(a0*rden + bv.x);
      o.y = eluf(a1*rden + bv.y);
      o.z = eluf(a2*rden + bv.z);
      o.w = eluf(a3*rden + bv.w);
      *(float4*)&out[(size_t)n*128 + l5*4] = o;
    }
  } else {
    int h = lane >> 4;
    float den = (h==0) ? dsum.x : (h==1) ? dsum.y : (h==2) ? dsum.z : dsum.w;
    float rden = 1.f / fmaxf(den, 1e-9f);
    float a0=0.f, a1=0.f, a2=0.f, a3=0.f;
    for (int base = beg; base < end; base += 4){    // 4 edges/iter, full wave each
      int   ss[4]; float ev[4];
      #pragma unroll
      for (int i = 0; i < 4; ++i){
        int e = base + i;
        bool ok = e < end;
        int  ec = ok ? e : beg;
        ss[i] = csr_src[ec];
        ev[i] = ok ? expv[(size_t)e*4 + h] : 0.f;
      }
      float4 v0, v1, v2, v3;
      gather4(&feat[(size_t)ss[0]*256 + lane*4], &feat[(size_t)ss[1]*256 + lane*4],
              &feat[(size_t)ss[2]*256 + lane*4], &feat[(size_t)ss[3]*256 + lane*4],
              v0, v1, v2, v3);
      a0 += ev[0]*v0.x; a1 += ev[0]*v0.y; a2 += ev[0]*v0.z; a3 += ev[0]*v0.w;
      a0 += ev[1]*v1.x; a1 += ev[1]*v1.y; a2 += ev[1]*v1.z; a3 += ev[1]*v1.w;
      a0 += ev[2]*v2.x; a1 += ev[2]*v2.y; a2 += ev[2]*v2.z; a3 += ev[2]*v2.w;
      a0 += ev[3]*v3.x; a1 += ev[3]*v3.y; a2 += ev[3]*v3.z; a3 += ev[3]*v3.w;
    }
    float4 bv = *(const float4*)&bias[lane*4];
    float v0 = a0*rden + bv.x;
    float v1 = a1*rden + bv.y;
    float v2 = a2*rden + bv.z;
    float v3 = a3*rden + bv.w;
    // mean over heads: combine lanes with equal (lane & 15)
    v0 += __shfl_xor(v0, 16); v0 += __shfl_xor(v0, 32);
    v1 += __shfl_xor(v1, 16); v1 += __shfl_xor(v1, 32);
    v2 += __shfl_xor(v2, 16); v2 += __shfl_xor(v2, 32);
    v3 += __shfl_xor(v3, 16); v3 += __shfl_xor(v3, 32);
    if (lane < 16)
      *(float4*)&out[(size_t)n*64 + lane*4] =
        make_float4(v0*0.25f, v1*0.25f, v2*0.25f, v3*0.25f);
  }
}

extern "C" void kernel_launch(void* const* d_in, const int* in_sizes, int n_in,
                              void* d_out, int out_size, void* d_ws, size_t ws_size,
                              hipStream_t stream){
  const float* x   = (const float*)d_in[0];
  const int*   src = (const int*)  d_in[1];
  const int*   dst = (const int*)  d_in[2];
  const float* W[4]  = {(const float*)d_in[3],  (const float*)d_in[7],
                        (const float*)d_in[11], (const float*)d_in[15]};
  const float* al[4] = {(const float*)d_in[4],  (const float*)d_in[8],
                        (const float*)d_in[12], (const float*)d_in[16]};
  const float* ar[4] = {(const float*)d_in[5],  (const float*)d_in[9],
                        (const float*)d_in[13], (const float*)d_in[17]};
  const float* b[4]  = {(const float*)d_in[6],  (const float*)d_in[10],
                        (const float*)d_in[14], (const float*)d_in[18]};

  char* ws = (char*)d_ws;
  float* bufH    = (float*)(ws);                  // 25,600,000
  float* feat    = (float*)(ws + 25600000);       // 51,200,000
  float* el      = (float*)(ws + 76800000);       // 800,000
  float* er      = (float*)(ws + 77600000);       // 800,000
  int*   offs    = (int*)  (ws + 78400000);       // 200,004 (padded)
  int*   cur     = (int*)  (ws + 78600032);       // 200,000
  int*   bsum    = (int*)  (ws + 78800032);       // 1,024
  int*   csr_src = (int*)  (ws + 78801056);       // 3,200,000
  int*   csr_dst = (int*)  (ws + 82001056);       // 3,200,000
  float* expv    = (float*)(ws + 85201056);       // 12,800,000   (end ~98 MB)

  // ---- CSR build (per call; ws is re-poisoned) ----
  (void)hipMemsetAsync(cur, 0, N_NODES*sizeof(int), stream);
  k_hist   <<<3125, 256, 0, stream>>>(dst, cur);
  k_scan1  <<<196,  256, 0, stream>>>(cur, offs, bsum);
  k_scan2  <<<1,    256, 0, stream>>>(bsum, 196);
  k_scan3  <<<196,  256, 0, stream>>>(offs, bsum, cur);
  k_scatter<<<3125, 256, 0, stream>>>(src, dst, cur, csr_src, csr_dst);

  // ---- layer 1..3 (HF=128, F=32) ----
  k_gemm<128,1><<<dim3(782,2), 256, 0, stream>>>(x, W[0], feat, al[0], ar[0], el, er);
  k_exp        <<<3125, 256, 0, stream>>>(csr_src, csr_dst, el, er, expv);
  k_agg<32,false,1><<<12500, 256, 0, stream>>>(offs, csr_src, expv, feat, b[0], bufH);

  k_gemm<128,2><<<dim3(782,2), 256, 0, stream>>>(bufH, W[1], feat, al[1], ar[1], el, er);
  k_exp        <<<3125, 256, 0, stream>>>(csr_src, csr_dst, el, er, expv);
  k_agg<32,false,2><<<12500, 256, 0, stream>>>(offs, csr_src, expv, feat, b[1], bufH);

  k_gemm<128,3><<<dim3(782,2), 256, 0, stream>>>(bufH, W[2], feat, al[2], ar[2], el, er);
  k_exp        <<<3125, 256, 0, stream>>>(csr_src, csr_dst, el, er, expv);
  k_agg<32,false,3><<<12500, 256, 0, stream>>>(offs, csr_src, expv, feat, b[2], bufH);

  // ---- layer 4 (HF=256, F=64) + head-mean ----
  k_gemm<256,4><<<dim3(782,4), 256, 0, stream>>>(bufH, W[3], feat, al[3], ar[3], el, er);
  k_exp        <<<3125, 256, 0, stream>>>(csr_src, csr_dst, el, er, expv);
  k_agg<64,true,4><<<12500, 256, 0, stream>>>(offs, csr_src, expv, feat, b[3], (float*)d_out);
}

// Round 8
// 656.245 us; speedup vs baseline: 1.2219x; 1.0202x over previous
//
#include <hip/hip_runtime.h>

#define N_NODES 50000
#define N_EDGES 800000

__device__ __forceinline__ float lrelu(float x){ return x > 0.f ? x : 0.2f*x; }
__device__ __forceinline__ float eluf (float x){ return x > 0.f ? x : __expf(x)-1.f; }

// ---------------- CSR build ----------------
__global__ void k_hist(const int* __restrict__ dst, int* __restrict__ cnt){
  int e = blockIdx.x*256 + threadIdx.x;
  if (e < N_EDGES) atomicAdd(&cnt[dst[e]], 1);
}

__global__ void k_scan1(const int* __restrict__ cnt, int* __restrict__ offs, int* __restrict__ bsum){
  __shared__ int tmp[256];
  int tid = threadIdx.x; int i = blockIdx.x*256 + tid;
  int v = (i < N_NODES) ? cnt[i] : 0;
  tmp[tid] = v; __syncthreads();
  for (int d = 1; d < 256; d <<= 1){
    int t = (tid >= d) ? tmp[tid-d] : 0;
    __syncthreads();
    tmp[tid] += t;
    __syncthreads();
  }
  if (i < N_NODES) offs[i] = tmp[tid] - v;          // exclusive within chunk
  if (tid == 255) bsum[blockIdx.x] = tmp[tid];       // chunk total
}

__global__ void k_scan2(int* __restrict__ bsum, int nb){
  __shared__ int tmp[256];
  int tid = threadIdx.x;
  int v = (tid < nb) ? bsum[tid] : 0;
  tmp[tid] = v; __syncthreads();
  for (int d = 1; d < 256; d <<= 1){
    int t = (tid >= d) ? tmp[tid-d] : 0;
    __syncthreads();
    tmp[tid] += t;
    __syncthreads();
  }
  if (tid < nb) bsum[tid] = tmp[tid] - v;            // exclusive chunk offsets
}

__global__ void k_scan3(int* __restrict__ offs, const int* __restrict__ bsum, int* __restrict__ cur){
  int i = blockIdx.x*256 + threadIdx.x;
  if (i < N_NODES){
    int o = offs[i] + bsum[blockIdx.x];
    offs[i] = o; cur[i] = o;
  }
  if (i == 0) offs[N_NODES] = N_EDGES;
}

__global__ void k_scatter(const int* __restrict__ src, const int* __restrict__ dst,
                          int* __restrict__ cur, int* __restrict__ csr_src){
  int e = blockIdx.x*256 + threadIdx.x;
  if (e < N_EDGES){
    int pos = atomicAdd(&cur[dst[e]], 1);
    csr_src[pos] = src[e];
  }
}

// ---------------- GEMM: feat[N,HF] = h[N,128] @ W[128,HF], fused el/er ----------------
template<int HF, int LAYER>
__global__ __launch_bounds__(256) void k_gemm(const float* __restrict__ h,
                                              const float* __restrict__ W,
                                              float* __restrict__ feat,
                                              const float* __restrict__ al,
                                              const float* __restrict__ ar,
                                              float* __restrict__ el,
                                              float* __restrict__ er){
  __shared__ float Wl[64*64];    // [k][j]
  __shared__ float hTl[64*68];   // [k][r], pad 68 breaks transpose-store conflicts
  int tid = threadIdx.x;
  int tx = tid & 15, ty = tid >> 4;
  int row0 = blockIdx.x * 64;
  int col0 = blockIdx.y * 64;
  float acc[4][4] = {};
  for (int kc = 0; kc < 2; ++kc){
    #pragma unroll
    for (int p = 0; p < 4; ++p){              // stage W chunk [64k x 64j]
      int k = p*16 + ty;
      float4 wv = *(const float4*)&W[(size_t)(kc*64 + k)*HF + col0 + tx*4];
      *(float4*)&Wl[k*64 + tx*4] = wv;
    }
    #pragma unroll
    for (int p = 0; p < 4; ++p){              // stage h chunk transposed
      int idx = (p*256 + tid)*4;              // 0..4095
      int r = idx >> 6, c = idx & 63;
      float4 hv = make_float4(0.f,0.f,0.f,0.f);
      int row = row0 + r;
      if (row < N_NODES) hv = *(const float4*)&h[(size_t)row*128 + kc*64 + c];
      hTl[(c+0)*68 + r] = hv.x;
      hTl[(c+1)*68 + r] = hv.y;
      hTl[(c+2)*68 + r] = hv.z;
      hTl[(c+3)*68 + r] = hv.w;
    }
    __syncthreads();
    #pragma unroll 8
    for (int k = 0; k < 64; ++k){
      float4 hv = *(const float4*)&hTl[k*68 + ty*4];
      float4 wv = *(const float4*)&Wl [k*64 + tx*4];
      acc[0][0] += hv.x*wv.x; acc[0][1] += hv.x*wv.y; acc[0][2] += hv.x*wv.z; acc[0][3] += hv.x*wv.w;
      acc[1][0] += hv.y*wv.x; acc[1][1] += hv.y*wv.y; acc[1][2] += hv.y*wv.z; acc[1][3] += hv.y*wv.w;
      acc[2][0] += hv.z*wv.x; acc[2][1] += hv.z*wv.y; acc[2][2] += hv.z*wv.z; acc[2][3] += hv.z*wv.w;
      acc[3][0] += hv.w*wv.x; acc[3][1] += hv.w*wv.y; acc[3][2] += hv.w*wv.z; acc[3][3] += hv.w*wv.w;
    }
    __syncthreads();
  }
  #pragma unroll
  for (int i = 0; i < 4; ++i){
    int row = row0 + ty*4 + i;
    if (row < N_NODES)
      *(float4*)&feat[(size_t)row*HF + col0 + tx*4] =
        make_float4(acc[i][0], acc[i][1], acc[i][2], acc[i][3]);
  }
  // ---- fused el/er epilogue ----
  constexpr int F = HF/4;               // head dim
  constexpr int G = (F == 32) ? 8 : 16; // tx-lanes per head
  float4 alv = *(const float4*)&al[col0 + tx*4];
  float4 arv = *(const float4*)&ar[col0 + tx*4];
  int hidx = (col0 + tx*4) / F;
  #pragma unroll
  for (int i = 0; i < 4; ++i){
    float pl = acc[i][0]*alv.x + acc[i][1]*alv.y + acc[i][2]*alv.z + acc[i][3]*alv.w;
    float pr = acc[i][0]*arv.x + acc[i][1]*arv.y + acc[i][2]*arv.z + acc[i][3]*arv.w;
    #pragma unroll
    for (int m = 1; m < G; m <<= 1){
      pl += __shfl_xor(pl, m);
      pr += __shfl_xor(pr, m);
    }
    int row = row0 + ty*4 + i;
    if ((tx & (G-1)) == 0 && row < N_NODES){
      el[row*4 + hidx] = pl;
      er[row*4 + hidx] = pr;
    }
  }
}

// ---------------- fused single-pass softmax + aggregation (1 wave / node) ----------------
// out = (Σ_e ev·feat[src_e]) / (Σ_e ev),  ev = exp(lrelu(el[src]+er[n])).
// Denominator accumulated ALONGSIDE the weighted sum (no pass A, no expv
// buffer, no k_exp kernel). el is an 800 KB table -> random 4B reads are
// L2-resident. Gather structure = R2's best (two 512B rows per instruction
// for F=32; one 1KB row for F=64) — the ~110 µs/layer request-rate floor.
template<int F, bool FINAL, int LAYER>
__global__ __launch_bounds__(256) void k_agg(const int* __restrict__ offs,
        const int* __restrict__ csr_src, const float* __restrict__ el,
        const float* __restrict__ er, const float* __restrict__ feat,
        const float* __restrict__ bias, float* __restrict__ out){
  int lane = threadIdx.x & 63;
  int n = (blockIdx.x*256 + threadIdx.x) >> 6;   // 12500 blocks * 4 waves = 50000 exactly
  if (n >= N_NODES) return;
  int beg = offs[n], end = offs[n+1];
  float4 er4 = ((const float4*)er)[n];

  if (F == 32){
    int half = lane >> 5;        // which edge of the pair
    int l5   = lane & 31;        // feature slot: floats l5*4..l5*4+3 of 128
    int h    = l5 >> 3;
    float er_h = (h==0) ? er4.x : (h==1) ? er4.y : (h==2) ? er4.z : er4.w;
    float a0=0.f, a1=0.f, a2=0.f, a3=0.f, ds=0.f;
    #pragma unroll 2
    for (int base = beg; base < end; base += 2){
      int e = base + half;
      if (e < end){
        int s = csr_src[e];
        float ev = __expf(lrelu(el[s*4 + h] + er_h));
        ds += ev;
        float4 v = *(const float4*)&feat[(size_t)s*128 + l5*4];
        a0 += ev*v.x; a1 += ev*v.y; a2 += ev*v.z; a3 += ev*v.w;
      }
    }
    ds += __shfl_xor(ds, 32);
    a0 += __shfl_xor(a0, 32);
    a1 += __shfl_xor(a1, 32);
    a2 += __shfl_xor(a2, 32);
    a3 += __shfl_xor(a3, 32);
    if (half == 0){
      float rden = 1.f / fmaxf(ds, 1e-9f);
      float4 bv = *(const float4*)&bias[l5*4];
      float4 o;
      o.x = eluf(a0*rden + bv.x);
      o.y = eluf(a1*rden + bv.y);
      o.z = eluf(a2*rden + bv.z);
      o.w = eluf(a3*rden + bv.w);
      *(float4*)&out[(size_t)n*128 + l5*4] = o;
    }
  } else {
    int h = lane >> 4;
    float er_h = (h==0) ? er4.x : (h==1) ? er4.y : (h==2) ? er4.z : er4.w;
    float a0=0.f, a1=0.f, a2=0.f, a3=0.f, ds=0.f;
    #pragma unroll 2
    for (int e = beg; e < end; ++e){
      int s = csr_src[e];
      float ev = __expf(lrelu(el[s*4 + h] + er_h));
      ds += ev;
      float4 v = *(const float4*)&feat[(size_t)s*256 + lane*4];
      a0 += ev*v.x; a1 += ev*v.y; a2 += ev*v.z; a3 += ev*v.w;
    }
    float rden = 1.f / fmaxf(ds, 1e-9f);
    float4 bv = *(const float4*)&bias[lane*4];
    float v0 = a0*rden + bv.x;
    float v1 = a1*rden + bv.y;
    float v2 = a2*rden + bv.z;
    float v3 = a3*rden + bv.w;
    // mean over heads: combine lanes with equal (lane & 15)
    v0 += __shfl_xor(v0, 16); v0 += __shfl_xor(v0, 32);
    v1 += __shfl_xor(v1, 16); v1 += __shfl_xor(v1, 32);
    v2 += __shfl_xor(v2, 16); v2 += __shfl_xor(v2, 32);
    v3 += __shfl_xor(v3, 16); v3 += __shfl_xor(v3, 32);
    if (lane < 16)
      *(float4*)&out[(size_t)n*64 + lane*4] =
        make_float4(v0*0.25f, v1*0.25f, v2*0.25f, v3*0.25f);
  }
}

extern "C" void kernel_launch(void* const* d_in, const int* in_sizes, int n_in,
                              void* d_out, int out_size, void* d_ws, size_t ws_size,
                              hipStream_t stream){
  const float* x   = (const float*)d_in[0];
  const int*   src = (const int*)  d_in[1];
  const int*   dst = (const int*)  d_in[2];
  const float* W[4]  = {(const float*)d_in[3],  (const float*)d_in[7],
                        (const float*)d_in[11], (const float*)d_in[15]};
  const float* al[4] = {(const float*)d_in[4],  (const float*)d_in[8],
                        (const float*)d_in[12], (const float*)d_in[16]};
  const float* ar[4] = {(const float*)d_in[5],  (const float*)d_in[9],
                        (const float*)d_in[13], (const float*)d_in[17]};
  const float* b[4]  = {(const float*)d_in[6],  (const float*)d_in[10],
                        (const float*)d_in[14], (const float*)d_in[18]};

  char* ws = (char*)d_ws;
  float* bufH    = (float*)(ws);                  // 25,600,000
  float* feat    = (float*)(ws + 25600000);       // 51,200,000
  float* el      = (float*)(ws + 76800000);       // 800,000
  float* er      = (float*)(ws + 77600000);       // 800,000
  int*   offs    = (int*)  (ws + 78400000);       // 200,004 (padded)
  int*   cur     = (int*)  (ws + 78600032);       // 200,000
  int*   bsum    = (int*)  (ws + 78800032);       // 1,024
  int*   csr_src = (int*)  (ws + 78801056);       // 3,200,000  (end ~82 MB)

  // ---- CSR build (per call; ws is re-poisoned) ----
  (void)hipMemsetAsync(cur, 0, N_NODES*sizeof(int), stream);
  k_hist   <<<3125, 256, 0, stream>>>(dst, cur);
  k_scan1  <<<196,  256, 0, stream>>>(cur, offs, bsum);
  k_scan2  <<<1,    256, 0, stream>>>(bsum, 196);
  k_scan3  <<<196,  256, 0, stream>>>(offs, bsum, cur);
  k_scatter<<<3125, 256, 0, stream>>>(src, dst, cur, csr_src);

  // ---- layer 1..3 (HF=128, F=32) ----
  k_gemm<128,1><<<dim3(782,2), 256, 0, stream>>>(x, W[0], feat, al[0], ar[0], el, er);
  k_agg<32,false,1><<<12500, 256, 0, stream>>>(offs, csr_src, el, er, feat, b[0], bufH);

  k_gemm<128,2><<<dim3(782,2), 256, 0, stream>>>(bufH, W[1], feat, al[1], ar[1], el, er);
  k_agg<32,false,2><<<12500, 256, 0, stream>>>(offs, csr_src, el, er, feat, b[1], bufH);

  k_gemm<128,3><<<dim3(782,2), 256, 0, stream>>>(bufH, W[2], feat, al[2], ar[2], el, er);
  k_agg<32,false,3><<<12500, 256, 0, stream>>>(offs, csr_src, el, er, feat, b[2], bufH);

  // ---- layer 4 (HF=256, F=64) + head-mean ----
  k_gemm<256,4><<<dim3(782,4), 256, 0, stream>>>(bufH, W[3], feat, al[3], ar[3], el, er);
  k_agg<64,true,4><<<12500, 256, 0, stream>>>(offs, csr_src, el, er, feat, b[3], (float*)d_out);
}